// Round 6
// baseline (179.749 us; speedup 1.0000x reference)
//
#include <hip/hip_runtime.h>

// SparseWindowedAttention: B=1, S=4096, E=768, H=12, hd=64, window=128
// Inputs fp32 (converted to bf16 in ws), output fp32. MFMA bf16, fp32 accum.
//
//   c0: fused fp32->bf16 convert (x, Wqkv, Wo)
//   k1: qkv GEMM (M=4096,N=2304,K=768) -> scattered into head-split
//       Q/K/V[12][4096][64] bf16 (coalesced attention loads)
//   k2: windowed attention (S^T formulation) -> attn [4096][768] bf16
//   k3: out = attn @ Wo^T + bo (M=4096,N=768,K=768) -> fp32 d_out

typedef __attribute__((ext_vector_type(8))) short short8;
typedef __attribute__((ext_vector_type(4))) short short4v;
typedef __attribute__((ext_vector_type(4))) float f32x4;

#define S_LEN 4096
#define EMB   768
#define NH    12
#define HD    64
#define QT    64      // queries per attention block (16 per wave)
#define WMAX  128
#define NKT   20      // key tiles of 16 covering [q0-128, q0+192)
#define VSTR  332     // Vt row stride in shorts (664B): min-conflict b64 reads

// Device-only MFMA16 (host pass can't see amdgcn builtins; it only parses)
#if defined(__HIP_DEVICE_COMPILE__)
#define MFMA16(a, b, c) __builtin_amdgcn_mfma_f32_16x16x16bf16_1k(a, b, c, 0, 0, 0)
#else
#define MFMA16(a, b, c) (c)
#endif

__device__ __forceinline__ short f2bf(float f) {
    union { unsigned int i; float f; } c;
    c.f = f;
    unsigned int i = c.i;
    unsigned int r = (i + 0x7FFFu + ((i >> 16) & 1u)) >> 16;
    return (short)(unsigned short)r;
}

// fused fp32->bf16: segments [x | Wqkv | Wo], one float4 per thread
#define NX4  (S_LEN * EMB / 4)
#define NW4  (3 * EMB * EMB / 4)
#define NO4  (EMB * EMB / 4)
__global__ __launch_bounds__(256) void convert_all(
    const float* __restrict__ x, const float* __restrict__ wqkv,
    const float* __restrict__ wo, short* __restrict__ xb,
    short* __restrict__ wqkvb, short* __restrict__ wob)
{
    int i = blockIdx.x * 256 + threadIdx.x;
    const float* src; short* dst; int off;
    if (i < NX4)            { src = x;    dst = xb;    off = i; }
    else if (i < NX4 + NW4) { src = wqkv; dst = wqkvb; off = i - NX4; }
    else                    { src = wo;   dst = wob;   off = i - NX4 - NW4; }
    float4 v = ((const float4*)src)[off];
    short4v o = { f2bf(v.x), f2bf(v.y), f2bf(v.z), f2bf(v.w) };
    *(short4v*)(dst + (size_t)off * 4) = o;
}

// ---------------------------------------------------------------------------
// GEMM: C[m][n] = sum_k A[m][k]*B[n][k] + bias[n].  A:[M][K] B:[N][K] bf16.
// MODE 0: bf16 row-major [M][N] store (ws)    MODE 1: fp32 row-major (d_out)
// MODE 2: qkv head-split scatter into [3][12][4096][64] bf16
// 256 threads (4 waves), tile 128x128, BK=32, async global->LDS staging.
// ---------------------------------------------------------------------------
template <int MODE>
__global__ __launch_bounds__(256) void gemm_bt_bias(
    const short* __restrict__ A, const short* __restrict__ B,
    const float* __restrict__ bias, void* __restrict__ Cv,
    int M, int N, int K)
{
    __shared__ __align__(16) short As[128 * 32];
    __shared__ __align__(16) short Bs[128 * 32];

    const int t = threadIdx.x;
    const int w = t >> 6, l = t & 63;
    const int quad = l >> 4, lane16 = l & 15;
    const int m0 = blockIdx.y * 128, n0 = blockIdx.x * 128;
    const int wm = (w >> 1) * 64, wn = (w & 1) * 64;

    f32x4 acc[4][4];
#pragma unroll
    for (int i = 0; i < 4; ++i)
#pragma unroll
        for (int j = 0; j < 4; ++j) acc[i][j] = (f32x4){0.f, 0.f, 0.f, 0.f};

    for (int k0 = 0; k0 < K; k0 += 32) {
        // async global->LDS, 16B/lane: lds dst = wave-uniform base + lane*16
#pragma unroll
        for (int i = 0; i < 2; ++i) {
            int c = i * 256 + t;          // chunk id 0..511
            int r = c >> 2, kc = c & 3;   // row in tile, 8-elem col group
#if defined(__HIP_DEVICE_COMPILE__) && __has_builtin(__builtin_amdgcn_global_load_lds)
            __builtin_amdgcn_global_load_lds(
                (const __attribute__((address_space(1))) void*)(A + (size_t)(m0 + r) * K + k0 + kc * 8),
                (__attribute__((address_space(3))) void*)(As + c * 8), 16, 0, 0);
            __builtin_amdgcn_global_load_lds(
                (const __attribute__((address_space(1))) void*)(B + (size_t)(n0 + r) * K + k0 + kc * 8),
                (__attribute__((address_space(3))) void*)(Bs + c * 8), 16, 0, 0);
#else
            *(short8*)(As + c * 8) = *(const short8*)(A + (size_t)(m0 + r) * K + k0 + kc * 8);
            *(short8*)(Bs + c * 8) = *(const short8*)(B + (size_t)(n0 + r) * K + k0 + kc * 8);
#endif
        }
        __syncthreads();   // drains vmcnt (incl. lds-DMA) + lgkm

        short8 af[4], bfr[4];
#pragma unroll
        for (int mt = 0; mt < 4; ++mt)
            af[mt] = *(const short8*)(As + (wm + mt * 16 + lane16) * 32 + quad * 8);
#pragma unroll
        for (int nt = 0; nt < 4; ++nt)
            bfr[nt] = *(const short8*)(Bs + (wn + nt * 16 + lane16) * 32 + quad * 8);
#pragma unroll
        for (int mt = 0; mt < 4; ++mt)
#pragma unroll
            for (int nt = 0; nt < 4; ++nt)
                acc[mt][nt] = __builtin_amdgcn_mfma_f32_16x16x32_bf16(
                    af[mt], bfr[nt], acc[mt][nt], 0, 0, 0);
        __syncthreads();
    }

    // epilogue: D[row=quad*4+r][col=lane16] per 16x16 tile
#pragma unroll
    for (int nt = 0; nt < 4; ++nt) {
        int col = n0 + wn + nt * 16 + lane16;
        float bv = bias[col];
        // MODE 2: col -> (type, head, dim); dst = [ty][h][row][d]
        int h = col / 192;
        int rem = col - h * 192;
        int ty = rem >> 6, d = rem & 63;
        short* qdst = (short*)Cv + (((size_t)ty * NH + h) * S_LEN) * HD + d;
#pragma unroll
        for (int mt = 0; mt < 4; ++mt) {
#pragma unroll
            for (int r = 0; r < 4; ++r) {
                int row = m0 + wm + mt * 16 + quad * 4 + r;
                float v = acc[mt][nt][r] + bv;
                if (MODE == 0)
                    ((short*)Cv)[(size_t)row * N + col] = f2bf(v);
                else if (MODE == 1)
                    ((float*)Cv)[(size_t)row * N + col] = v;
                else
                    qdst[(size_t)row * HD] = f2bf(v);
            }
        }
    }
}

// ---------------------------------------------------------------------------
// Windowed attention, S^T formulation, head-split Q/K/V[12][4096][64] input.
// Block = (q-tile of 64, head); wave w owns queries [q0+w*16, q0+w*16+16),
// one query per lane16-column. Key window [q0-128, q0+192).
//   All global loads are coalesced (consecutive keys -> contiguous 128B rows).
//   St = K·Q^T via mfma(A=K, B=Q): C-layout row=key(quad*4+r), col=q(lane16).
//   P (C-layout) IS the B-operand of mfma_16x16x16 -> PV with no transpose.
//   O^T = V^T·P per 16-dim tile; V^T staged once in LDS.
// ---------------------------------------------------------------------------
__global__ __launch_bounds__(256) void attn_win(
    const short* __restrict__ qsplit, const int* __restrict__ wptr,
    short* __restrict__ attn_out)
{
    __shared__ __align__(16) short Vt[HD][VSTR];   // V^T: Vt[d][key], 42496 B

    const int t = threadIdx.x;
    const int w = t >> 6, l = t & 63;
    const int quad = l >> 4, lane16 = l & 15;
    const int h = blockIdx.y;
    const int q0 = blockIdx.x * QT;
    const int W = *wptr;
    const int kbase = q0 - WMAX;

    const short* Qh = qsplit + (size_t)h * S_LEN * HD;
    const short* Kh = qsplit + (size_t)(NH + h) * S_LEN * HD;
    const short* Vh = qsplit + (size_t)(2 * NH + h) * S_LEN * HD;

    // stage V transposed: Vt[d][kk] = V[kbase+kk][d]; global reads contiguous
    for (int c = t; c < 320 * 8; c += 256) {
        int kk = c >> 3;
        int dc = c & 7;
        int key = kbase + kk;
        int idx = min(max(key, 0), S_LEN - 1);
        short8 v = *(const short8*)(Vh + (size_t)idx * HD + dc * 8);
#pragma unroll
        for (int j = 0; j < 8; ++j)
            Vt[dc * 8 + j][kk] = v[j];
    }
    __syncthreads();   // the only barrier

    // Q as B-operand: B[n=q=lane16][k=dim=quad*8+j], two 32-dim halves
    const int qi = q0 + w * 16 + lane16;
    const short* qp = Qh + (size_t)qi * HD;
    short8 bq0 = *(const short8*)(qp + quad * 8);
    short8 bq1 = *(const short8*)(qp + 32 + quad * 8);

    // St[key][q] per 16-key tile; K A-frags coalesced from global (L2-hot)
    f32x4 sc[NKT];
#pragma unroll
    for (int kt = 0; kt < NKT; ++kt) {
        int key = kbase + kt * 16 + lane16;
        int idx = min(max(key, 0), S_LEN - 1);
        const short* kp = Kh + (size_t)idx * HD;
        short8 a0 = *(const short8*)(kp + quad * 8);
        short8 a1 = *(const short8*)(kp + 32 + quad * 8);
        f32x4 a = (f32x4){0.f, 0.f, 0.f, 0.f};
        a = __builtin_amdgcn_mfma_f32_16x16x32_bf16(a0, bq0, a, 0, 0, 0);
        a = __builtin_amdgcn_mfma_f32_16x16x32_bf16(a1, bq1, a, 0, 0, 0);
        sc[kt] = a;
    }

    // mask + scale + column(=q) max
    const float scale = 0.125f;  // 1/sqrt(64)
    float m = -1e30f;
#pragma unroll
    for (int kt = 0; kt < NKT; ++kt) {
#pragma unroll
        for (int r = 0; r < 4; ++r) {
            int key = kbase + kt * 16 + quad * 4 + r;
            int d = qi - key;
            int ad = d < 0 ? -d : d;
            bool valid = (key >= 0) && (key < S_LEN) && (ad <= W);
            float s = valid ? sc[kt][r] * scale : -1e30f;
            sc[kt][r] = s;
            m = fmaxf(m, s);
        }
    }
    m = fmaxf(m, __shfl_xor(m, 16, 64));
    m = fmaxf(m, __shfl_xor(m, 32, 64));

    float lsum = 0.f;
#pragma unroll
    for (int kt = 0; kt < NKT; ++kt) {
#pragma unroll
        for (int r = 0; r < 4; ++r) {
            float p = __expf(sc[kt][r] - m);
            sc[kt][r] = p;
            lsum += p;
        }
    }
    lsum += __shfl_xor(lsum, 16, 64);
    lsum += __shfl_xor(lsum, 32, 64);
    const float rl = 1.f / fmaxf(lsum, 1e-30f);

    // PV: O^T[d][q] += V^T[d][k] * P[q][k]; P C-layout == B-frag of 16x16x16
    f32x4 oacc[4];
#pragma unroll
    for (int nt = 0; nt < 4; ++nt) oacc[nt] = (f32x4){0.f, 0.f, 0.f, 0.f};

#pragma unroll
    for (int kt = 0; kt < NKT; ++kt) {
        short4v pb = { f2bf(sc[kt][0]), f2bf(sc[kt][1]),
                       f2bf(sc[kt][2]), f2bf(sc[kt][3]) };
#pragma unroll
        for (int nt = 0; nt < 4; ++nt) {
            short4v va = *(const short4v*)(&Vt[nt * 16 + lane16][kt * 16 + quad * 4]);
            oacc[nt] = MFMA16(va, pb, oacc[nt]);
        }
    }

    // normalize + store: O^T C-layout row=d=quad*4+r, col=q=lane16 -> 8B stores
#pragma unroll
    for (int nt = 0; nt < 4; ++nt) {
        short4v ob = { f2bf(oacc[nt][0] * rl), f2bf(oacc[nt][1] * rl),
                       f2bf(oacc[nt][2] * rl), f2bf(oacc[nt][3] * rl) };
        *(short4v*)(attn_out + (size_t)qi * EMB + h * HD + nt * 16 + quad * 4) = ob;
    }
}

extern "C" void kernel_launch(void* const* d_in, const int* in_sizes, int n_in,
                              void* d_out, int out_size, void* d_ws, size_t ws_size,
                              hipStream_t stream) {
    const float* x    = (const float*)d_in[0];   // [4096][768] fp32
    const float* Wqkv = (const float*)d_in[1];   // [2304][768] fp32
    const float* bqkv = (const float*)d_in[2];   // [2304] fp32
    const float* Wo   = (const float*)d_in[3];   // [768][768] fp32
    const float* bo   = (const float*)d_in[4];   // [768] fp32
    const int*   wptr = (const int*)d_in[5];     // window_size

    float* out = (float*)d_out;                  // [4096][768] fp32

    // workspace (bf16 shorts), 16B-aligned offsets
    short* xb     = (short*)d_ws;                       //  4096*768
    short* wqkvb  = xb     + (size_t)S_LEN * EMB;       //  2304*768
    short* wob    = wqkvb  + (size_t)3 * EMB * EMB;     //   768*768
    short* qsplit = wob    + (size_t)EMB * EMB;         //  3*12*4096*64
    short* attn   = qsplit + (size_t)3 * NH * S_LEN * HD; // 4096*768

    dim3 blk(256);
    convert_all<<<dim3((NX4 + NW4 + NO4) / 256), blk, 0, stream>>>(
        x, Wqkv, Wo, xb, wqkvb, wob);
    gemm_bt_bias<2><<<dim3(2304 / 128, S_LEN / 128), blk, 0, stream>>>(
        xb, wqkvb, bqkv, qsplit, S_LEN, 2304, EMB);
    attn_win<<<dim3(S_LEN / QT, NH), blk, 0, stream>>>(qsplit, wptr, attn);
    gemm_bt_bias<1><<<dim3(EMB / 128, S_LEN / 128), blk, 0, stream>>>(
        attn, wob, bo, out, S_LEN, EMB, EMB);
}

// Round 7
// 156.124 us; speedup vs baseline: 1.1513x; 1.1513x over previous
//
#include <hip/hip_runtime.h>

// SparseWindowedAttention: B=1, S=4096, E=768, H=12, hd=64, window=128
// Inputs fp32 (converted to bf16 in ws), output fp32. MFMA bf16, fp32 accum.
//
//   c0: fused fp32->bf16 convert (x, Wqkv, Wo)
//   k1: qkv GEMM -> head-split Q/K/V[12][4096][64] bf16
//   k2: windowed attention: K via global_load_lds DMA (swizzled), V->regs,
//       LDS buffer reused K->V^T, S^T formulation, XCD-local block map
//   k3: out = attn @ Wo^T + bo -> fp32 d_out

typedef __attribute__((ext_vector_type(8))) short short8;
typedef __attribute__((ext_vector_type(4))) short short4v;
typedef __attribute__((ext_vector_type(4))) float f32x4;

#define S_LEN 4096
#define EMB   768
#define NH    12
#define HD    64
#define QT    64      // queries per attention block (16 per wave)
#define WMAX  128
#define NKT   20      // key tiles of 16 covering [q0-128, q0+192)
#define VSTR  332     // Vt row stride in shorts (664B)

#if defined(__HIP_DEVICE_COMPILE__)
#define MFMA16(a, b, c) __builtin_amdgcn_mfma_f32_16x16x16bf16_1k(a, b, c, 0, 0, 0)
#else
#define MFMA16(a, b, c) (c)
#endif

__device__ __forceinline__ short f2bf(float f) {
    union { unsigned int i; float f; } c;
    c.f = f;
    unsigned int i = c.i;
    unsigned int r = (i + 0x7FFFu + ((i >> 16) & 1u)) >> 16;
    return (short)(unsigned short)r;
}

// fused fp32->bf16: segments [x | Wqkv | Wo]
#define NX4  (S_LEN * EMB / 4)
#define NW4  (3 * EMB * EMB / 4)
#define NO4  (EMB * EMB / 4)
__global__ __launch_bounds__(256) void convert_all(
    const float* __restrict__ x, const float* __restrict__ wqkv,
    const float* __restrict__ wo, short* __restrict__ xb,
    short* __restrict__ wqkvb, short* __restrict__ wob)
{
    int i = blockIdx.x * 256 + threadIdx.x;
    const float* src; short* dst; int off;
    if (i < NX4)            { src = x;    dst = xb;    off = i; }
    else if (i < NX4 + NW4) { src = wqkv; dst = wqkvb; off = i - NX4; }
    else                    { src = wo;   dst = wob;   off = i - NX4 - NW4; }
    float4 v = ((const float4*)src)[off];
    short4v o = { f2bf(v.x), f2bf(v.y), f2bf(v.z), f2bf(v.w) };
    *(short4v*)(dst + (size_t)off * 4) = o;
}

// ---------------------------------------------------------------------------
// GEMM (unchanged from R6): C = A·B^T + bias. MODE 1: fp32 out, MODE 2:
// head-split qkv scatter. 128x128 tile, BK=32, global_load_lds staging.
// ---------------------------------------------------------------------------
template <int MODE>
__global__ __launch_bounds__(256) void gemm_bt_bias(
    const short* __restrict__ A, const short* __restrict__ B,
    const float* __restrict__ bias, void* __restrict__ Cv,
    int M, int N, int K)
{
    __shared__ __align__(16) short As[128 * 32];
    __shared__ __align__(16) short Bs[128 * 32];

    const int t = threadIdx.x;
    const int w = t >> 6, l = t & 63;
    const int quad = l >> 4, lane16 = l & 15;
    const int m0 = blockIdx.y * 128, n0 = blockIdx.x * 128;
    const int wm = (w >> 1) * 64, wn = (w & 1) * 64;

    f32x4 acc[4][4];
#pragma unroll
    for (int i = 0; i < 4; ++i)
#pragma unroll
        for (int j = 0; j < 4; ++j) acc[i][j] = (f32x4){0.f, 0.f, 0.f, 0.f};

    for (int k0 = 0; k0 < K; k0 += 32) {
#pragma unroll
        for (int i = 0; i < 2; ++i) {
            int c = i * 256 + t;
            int r = c >> 2, kc = c & 3;
#if defined(__HIP_DEVICE_COMPILE__) && __has_builtin(__builtin_amdgcn_global_load_lds)
            __builtin_amdgcn_global_load_lds(
                (const __attribute__((address_space(1))) void*)(A + (size_t)(m0 + r) * K + k0 + kc * 8),
                (__attribute__((address_space(3))) void*)(As + c * 8), 16, 0, 0);
            __builtin_amdgcn_global_load_lds(
                (const __attribute__((address_space(1))) void*)(B + (size_t)(n0 + r) * K + k0 + kc * 8),
                (__attribute__((address_space(3))) void*)(Bs + c * 8), 16, 0, 0);
#else
            *(short8*)(As + c * 8) = *(const short8*)(A + (size_t)(m0 + r) * K + k0 + kc * 8);
            *(short8*)(Bs + c * 8) = *(const short8*)(B + (size_t)(n0 + r) * K + k0 + kc * 8);
#endif
        }
        __syncthreads();

        short8 af[4], bfr[4];
#pragma unroll
        for (int mt = 0; mt < 4; ++mt)
            af[mt] = *(const short8*)(As + (wm + mt * 16 + lane16) * 32 + quad * 8);
#pragma unroll
        for (int nt = 0; nt < 4; ++nt)
            bfr[nt] = *(const short8*)(Bs + (wn + nt * 16 + lane16) * 32 + quad * 8);
#pragma unroll
        for (int mt = 0; mt < 4; ++mt)
#pragma unroll
            for (int nt = 0; nt < 4; ++nt)
                acc[mt][nt] = __builtin_amdgcn_mfma_f32_16x16x32_bf16(
                    af[mt], bfr[nt], acc[mt][nt], 0, 0, 0);
        __syncthreads();
    }

#pragma unroll
    for (int nt = 0; nt < 4; ++nt) {
        int col = n0 + wn + nt * 16 + lane16;
        float bv = bias[col];
        int h = col / 192;
        int rem = col - h * 192;
        int ty = rem >> 6, d = rem & 63;
        short* qdst = (short*)Cv + (((size_t)ty * NH + h) * S_LEN) * HD + d;
#pragma unroll
        for (int mt = 0; mt < 4; ++mt) {
#pragma unroll
            for (int r = 0; r < 4; ++r) {
                int row = m0 + wm + mt * 16 + quad * 4 + r;
                float v = acc[mt][nt][r] + bv;
                if (MODE == 0)
                    ((short*)Cv)[(size_t)row * N + col] = f2bf(v);
                else if (MODE == 1)
                    ((float*)Cv)[(size_t)row * N + col] = v;
                else
                    qdst[(size_t)row * HD] = f2bf(v);
            }
        }
    }
}

// ---------------------------------------------------------------------------
// Windowed attention, S^T formulation, LDS-staged K (DMA + XOR swizzle).
// 1-D grid of 768; XCD-aware map: xcd=id&7 owns q-tiles [8*xcd, 8*xcd+8)
// for every head -> neighboring windows share the XCD's L2.
// Phases: (a) issue K-DMA (swizzled) + V global->reg loads + Q frag loads
//         (b) barrier; scores from LDS K (b128, 2-way banks = free)
//         (c) softmax in registers
//         (d) barrier (WAR); write V^T from regs into SAME LDS; barrier
//         (e) PV via MFMA16 (P in-situ as B-frag); normalize; store
// LDS 42496 B, __launch_bounds__(256,3) -> 3 blocks/CU, VGPR cap ~170.
// ---------------------------------------------------------------------------
__global__ __launch_bounds__(256, 3) void attn_win(
    const short* __restrict__ qsplit, const int* __restrict__ wptr,
    short* __restrict__ attn_out)
{
    __shared__ __align__(16) short KV[64 * VSTR];   // 42496 B: K stage, then V^T

    const int t = threadIdx.x;
    const int w = t >> 6, l = t & 63;
    const int quad = l >> 4, lane16 = l & 15;

    const int id = blockIdx.x;
    const int xcd = id & 7, j = id >> 3;
    const int h = j >> 3;                       // 0..11
    const int q0 = ((xcd << 3) + (j & 7)) * QT; // q-tile, XCD-local
    const int W = *wptr;
    const int kbase = q0 - WMAX;

    const short* Qh = qsplit + (size_t)h * S_LEN * HD;
    const short* Kh = qsplit + (size_t)(NH + h) * S_LEN * HD;
    const short* Vh = qsplit + (size_t)(2 * NH + h) * S_LEN * HD;

    // (a) K -> LDS via DMA, XOR-swizzled: chunk c=(r,gs) holds global group
    //     g = gs ^ (r&7) of K-row r. 2560 chunks, 10 per thread.
#pragma unroll
    for (int i = 0; i < 10; ++i) {
        int c = i * 256 + t;
        int r = c >> 3, gs = c & 7;
        int g = gs ^ (r & 7);
        int idx = min(max(kbase + r, 0), S_LEN - 1);
#if defined(__HIP_DEVICE_COMPILE__) && __has_builtin(__builtin_amdgcn_global_load_lds)
        __builtin_amdgcn_global_load_lds(
            (const __attribute__((address_space(1))) void*)(Kh + (size_t)idx * HD + g * 8),
            (__attribute__((address_space(3))) void*)(KV + c * 8), 16, 0, 0);
#else
        *(short8*)(KV + c * 8) = *(const short8*)(Kh + (size_t)idx * HD + g * 8);
#endif
    }
    // V window -> registers (issues overlap the K DMA; consumed in phase d)
    short8 vbuf[10];
#pragma unroll
    for (int i = 0; i < 10; ++i) {
        int c = i * 256 + t;
        int kk = c >> 3, dc = c & 7;
        int idx = min(max(kbase + kk, 0), S_LEN - 1);
        vbuf[i] = *(const short8*)(Vh + (size_t)idx * HD + dc * 8);
    }
    // Q as B-operand: B[n=q=lane16][k=dim=quad*8+j]
    const int qi = q0 + w * 16 + lane16;
    const short* qp = Qh + (size_t)qi * HD;
    short8 bq0 = *(const short8*)(qp + quad * 8);
    short8 bq1 = *(const short8*)(qp + 32 + quad * 8);

    __syncthreads();   // (b) K resident in LDS (drains vmcnt incl. DMA)

    // scores from LDS: A-frag row kt*16+lane16, groups quad / quad+4
    // (swizzle: group g at slot g^(row&7); row&7 == lane16&7)
    f32x4 sc[NKT];
    const int s0 = (quad ^ (lane16 & 7)) * 8;
    const int s1 = ((quad + 4) ^ (lane16 & 7)) * 8;
#pragma unroll
    for (int kt = 0; kt < NKT; ++kt) {
        const short* kp = KV + (kt * 16 + lane16) * 64;
        short8 a0 = *(const short8*)(kp + s0);
        short8 a1 = *(const short8*)(kp + s1);
        f32x4 a = (f32x4){0.f, 0.f, 0.f, 0.f};
        a = __builtin_amdgcn_mfma_f32_16x16x32_bf16(a0, bq0, a, 0, 0, 0);
        a = __builtin_amdgcn_mfma_f32_16x16x32_bf16(a1, bq1, a, 0, 0, 0);
        sc[kt] = a;
    }

    // (c) mask + scale + column(=q) softmax, all in registers
    const float scale = 0.125f;  // 1/sqrt(64)
    float m = -1e30f;
#pragma unroll
    for (int kt = 0; kt < NKT; ++kt) {
#pragma unroll
        for (int r = 0; r < 4; ++r) {
            int key = kbase + kt * 16 + quad * 4 + r;
            int d = qi - key;
            int ad = d < 0 ? -d : d;
            bool valid = (key >= 0) && (key < S_LEN) && (ad <= W);
            float s = valid ? sc[kt][r] * scale : -1e30f;
            sc[kt][r] = s;
            m = fmaxf(m, s);
        }
    }
    m = fmaxf(m, __shfl_xor(m, 16, 64));
    m = fmaxf(m, __shfl_xor(m, 32, 64));

    float lsum = 0.f;
#pragma unroll
    for (int kt = 0; kt < NKT; ++kt) {
#pragma unroll
        for (int r = 0; r < 4; ++r) {
            float p = __expf(sc[kt][r] - m);
            sc[kt][r] = p;
            lsum += p;
        }
    }
    lsum += __shfl_xor(lsum, 16, 64);
    lsum += __shfl_xor(lsum, 32, 64);
    const float rl = 1.f / fmaxf(lsum, 1e-30f);

    // (d) reuse LDS for V^T
    __syncthreads();   // WAR: all score reads of KV complete
    {
        short(*Vt)[VSTR] = (short(*)[VSTR])KV;
#pragma unroll
        for (int i = 0; i < 10; ++i) {
            int c = i * 256 + t;
            int kk = c >> 3, dc = c & 7;
#pragma unroll
            for (int jj = 0; jj < 8; ++jj)
                Vt[dc * 8 + jj][kk] = vbuf[i][jj];
        }
    }
    __syncthreads();   // V^T visible

    // (e) PV: O^T[d][q] += V^T[d][k]·P[q][k]; P C-layout == B-frag of 16x16x16
    short(*Vt)[VSTR] = (short(*)[VSTR])KV;
    f32x4 oacc[4];
#pragma unroll
    for (int nt = 0; nt < 4; ++nt) oacc[nt] = (f32x4){0.f, 0.f, 0.f, 0.f};

#pragma unroll
    for (int kt = 0; kt < NKT; ++kt) {
        short4v pb = { f2bf(sc[kt][0]), f2bf(sc[kt][1]),
                       f2bf(sc[kt][2]), f2bf(sc[kt][3]) };
#pragma unroll
        for (int nt = 0; nt < 4; ++nt) {
            short4v va = *(const short4v*)(&Vt[nt * 16 + lane16][kt * 16 + quad * 4]);
            oacc[nt] = MFMA16(va, pb, oacc[nt]);
        }
    }

    // normalize + store: O^T row=d=quad*4+r, col=q=lane16 -> 8B stores
#pragma unroll
    for (int nt = 0; nt < 4; ++nt) {
        short4v ob = { f2bf(oacc[nt][0] * rl), f2bf(oacc[nt][1] * rl),
                       f2bf(oacc[nt][2] * rl), f2bf(oacc[nt][3] * rl) };
        *(short4v*)(attn_out + (size_t)qi * EMB + h * HD + nt * 16 + quad * 4) = ob;
    }
}

extern "C" void kernel_launch(void* const* d_in, const int* in_sizes, int n_in,
                              void* d_out, int out_size, void* d_ws, size_t ws_size,
                              hipStream_t stream) {
    const float* x    = (const float*)d_in[0];
    const float* Wqkv = (const float*)d_in[1];
    const float* bqkv = (const float*)d_in[2];
    const float* Wo   = (const float*)d_in[3];
    const float* bo   = (const float*)d_in[4];
    const int*   wptr = (const int*)d_in[5];

    float* out = (float*)d_out;

    short* xb     = (short*)d_ws;
    short* wqkvb  = xb     + (size_t)S_LEN * EMB;
    short* wob    = wqkvb  + (size_t)3 * EMB * EMB;
    short* qsplit = wob    + (size_t)EMB * EMB;
    short* attn   = qsplit + (size_t)3 * NH * S_LEN * HD;

    dim3 blk(256);
    convert_all<<<dim3((NX4 + NW4 + NO4) / 256), blk, 0, stream>>>(
        x, Wqkv, Wo, xb, wqkvb, wob);
    gemm_bt_bias<2><<<dim3(2304 / 128, S_LEN / 128), blk, 0, stream>>>(
        xb, wqkvb, bqkv, qsplit, S_LEN, 2304, EMB);
    attn_win<<<dim3(S_LEN / QT * NH), blk, 0, stream>>>(qsplit, wptr, attn);
    gemm_bt_bias<1><<<dim3(EMB / 128, S_LEN / 128), blk, 0, stream>>>(
        attn, wob, bo, out, S_LEN, EMB, EMB);
}

// Round 8
// 150.764 us; speedup vs baseline: 1.1923x; 1.0356x over previous
//
#include <hip/hip_runtime.h>

// SparseWindowedAttention: B=1, S=4096, E=768, H=12, hd=64, window=128
// Inputs fp32 (converted to bf16 in ws), output fp32. MFMA bf16, fp32 accum.
//
//   c0: fused fp32->bf16 convert (x, Wqkv, Wo)
//   k1: qkv GEMM (double-buffered global_load_lds pipeline) -> head-split
//       Q/K/V[12][4096][64] bf16
//   k2: windowed attention (unchanged from R7)
//   k3: out = attn @ Wo^T + bo (same dbuf GEMM) -> fp32 d_out

typedef __attribute__((ext_vector_type(8))) short short8;
typedef __attribute__((ext_vector_type(4))) short short4v;
typedef __attribute__((ext_vector_type(4))) float f32x4;

#define S_LEN 4096
#define EMB   768
#define NH    12
#define HD    64
#define QT    64      // queries per attention block (16 per wave)
#define WMAX  128
#define NKT   20      // key tiles of 16 covering [q0-128, q0+192)
#define VSTR  332     // Vt row stride in shorts (664B)

#if defined(__HIP_DEVICE_COMPILE__)
#define MFMA16(a, b, c) __builtin_amdgcn_mfma_f32_16x16x16bf16_1k(a, b, c, 0, 0, 0)
#else
#define MFMA16(a, b, c) (c)
#endif

__device__ __forceinline__ short f2bf(float f) {
    union { unsigned int i; float f; } c;
    c.f = f;
    unsigned int i = c.i;
    unsigned int r = (i + 0x7FFFu + ((i >> 16) & 1u)) >> 16;
    return (short)(unsigned short)r;
}

// fused fp32->bf16: segments [x | Wqkv | Wo]
#define NX4  (S_LEN * EMB / 4)
#define NW4  (3 * EMB * EMB / 4)
#define NO4  (EMB * EMB / 4)
__global__ __launch_bounds__(256) void convert_all(
    const float* __restrict__ x, const float* __restrict__ wqkv,
    const float* __restrict__ wo, short* __restrict__ xb,
    short* __restrict__ wqkvb, short* __restrict__ wob)
{
    int i = blockIdx.x * 256 + threadIdx.x;
    const float* src; short* dst; int off;
    if (i < NX4)            { src = x;    dst = xb;    off = i; }
    else if (i < NX4 + NW4) { src = wqkv; dst = wqkvb; off = i - NX4; }
    else                    { src = wo;   dst = wob;   off = i - NX4 - NW4; }
    float4 v = ((const float4*)src)[off];
    short4v o = { f2bf(v.x), f2bf(v.y), f2bf(v.z), f2bf(v.w) };
    *(short4v*)(dst + (size_t)off * 4) = o;
}

// ---------------------------------------------------------------------------
// GEMM: C = A·B^T + bias, double-buffered DMA pipeline.
// Per iter: barrier -> issue DMA for tile k+1 into other buffer -> compute
// tile k. DMA latency is covered by the compute phase; 1 barrier/iter.
// WAR safe: barrier's lgkmcnt drains iter k-1's ds_reads before overwrite.
// MODE 1: fp32 row-major out.  MODE 2: head-split qkv scatter.
// ---------------------------------------------------------------------------
template <int MODE>
__global__ __launch_bounds__(256) void gemm_bt_bias(
    const short* __restrict__ A, const short* __restrict__ B,
    const float* __restrict__ bias, void* __restrict__ Cv,
    int M, int N, int K)
{
    __shared__ __align__(16) short As[2][128 * 32];
    __shared__ __align__(16) short Bs[2][128 * 32];

    const int t = threadIdx.x;
    const int w = t >> 6, l = t & 63;
    const int quad = l >> 4, lane16 = l & 15;
    const int m0 = blockIdx.y * 128, n0 = blockIdx.x * 128;
    const int wm = (w >> 1) * 64, wn = (w & 1) * 64;

    f32x4 acc[4][4];
#pragma unroll
    for (int i = 0; i < 4; ++i)
#pragma unroll
        for (int j = 0; j < 4; ++j) acc[i][j] = (f32x4){0.f, 0.f, 0.f, 0.f};

    const int NKI = K >> 5;

    auto stage = [&](int ki, int b) {
#pragma unroll
        for (int i = 0; i < 2; ++i) {
            int c = i * 256 + t;          // chunk 0..511
            int r = c >> 2, kc = c & 3;   // tile row, 8-elem col group
#if defined(__HIP_DEVICE_COMPILE__) && __has_builtin(__builtin_amdgcn_global_load_lds)
            __builtin_amdgcn_global_load_lds(
                (const __attribute__((address_space(1))) void*)(A + (size_t)(m0 + r) * K + ki * 32 + kc * 8),
                (__attribute__((address_space(3))) void*)(As[b] + c * 8), 16, 0, 0);
            __builtin_amdgcn_global_load_lds(
                (const __attribute__((address_space(1))) void*)(B + (size_t)(n0 + r) * K + ki * 32 + kc * 8),
                (__attribute__((address_space(3))) void*)(Bs[b] + c * 8), 16, 0, 0);
#else
            *(short8*)(As[b] + c * 8) = *(const short8*)(A + (size_t)(m0 + r) * K + ki * 32 + kc * 8);
            *(short8*)(Bs[b] + c * 8) = *(const short8*)(B + (size_t)(n0 + r) * K + ki * 32 + kc * 8);
#endif
        }
    };

    stage(0, 0);
    for (int kb = 0; kb < NKI; ++kb) {
        const int cur = kb & 1;
        __syncthreads();                   // buf[cur] DMA drained; prev reads done
        if (kb + 1 < NKI) stage(kb + 1, cur ^ 1);   // fire-and-forget prefetch

        short8 af[4], bfr[4];
#pragma unroll
        for (int mt = 0; mt < 4; ++mt)
            af[mt] = *(const short8*)(As[cur] + (wm + mt * 16 + lane16) * 32 + quad * 8);
#pragma unroll
        for (int nt = 0; nt < 4; ++nt)
            bfr[nt] = *(const short8*)(Bs[cur] + (wn + nt * 16 + lane16) * 32 + quad * 8);
#pragma unroll
        for (int mt = 0; mt < 4; ++mt)
#pragma unroll
            for (int nt = 0; nt < 4; ++nt)
                acc[mt][nt] = __builtin_amdgcn_mfma_f32_16x16x32_bf16(
                    af[mt], bfr[nt], acc[mt][nt], 0, 0, 0);
    }

#pragma unroll
    for (int nt = 0; nt < 4; ++nt) {
        int col = n0 + wn + nt * 16 + lane16;
        float bv = bias[col];
        int h = col / 192;
        int rem = col - h * 192;
        int ty = rem >> 6, d = rem & 63;
        short* qdst = (short*)Cv + (((size_t)ty * NH + h) * S_LEN) * HD + d;
#pragma unroll
        for (int mt = 0; mt < 4; ++mt) {
#pragma unroll
            for (int r = 0; r < 4; ++r) {
                int row = m0 + wm + mt * 16 + quad * 4 + r;
                float v = acc[mt][nt][r] + bv;
                if (MODE == 0)
                    ((short*)Cv)[(size_t)row * N + col] = f2bf(v);
                else if (MODE == 1)
                    ((float*)Cv)[(size_t)row * N + col] = v;
                else
                    qdst[(size_t)row * HD] = f2bf(v);
            }
        }
    }
}

// ---------------------------------------------------------------------------
// Windowed attention — UNCHANGED from R7 (S^T formulation, K via swizzled
// global_load_lds, V->regs->LDS reuse, XCD-local block map).
// ---------------------------------------------------------------------------
__global__ __launch_bounds__(256, 3) void attn_win(
    const short* __restrict__ qsplit, const int* __restrict__ wptr,
    short* __restrict__ attn_out)
{
    __shared__ __align__(16) short KV[64 * VSTR];   // 42496 B: K stage, then V^T

    const int t = threadIdx.x;
    const int w = t >> 6, l = t & 63;
    const int quad = l >> 4, lane16 = l & 15;

    const int id = blockIdx.x;
    const int xcd = id & 7, j = id >> 3;
    const int h = j >> 3;
    const int q0 = ((xcd << 3) + (j & 7)) * QT;
    const int W = *wptr;
    const int kbase = q0 - WMAX;

    const short* Qh = qsplit + (size_t)h * S_LEN * HD;
    const short* Kh = qsplit + (size_t)(NH + h) * S_LEN * HD;
    const short* Vh = qsplit + (size_t)(2 * NH + h) * S_LEN * HD;

#pragma unroll
    for (int i = 0; i < 10; ++i) {
        int c = i * 256 + t;
        int r = c >> 3, gs = c & 7;
        int g = gs ^ (r & 7);
        int idx = min(max(kbase + r, 0), S_LEN - 1);
#if defined(__HIP_DEVICE_COMPILE__) && __has_builtin(__builtin_amdgcn_global_load_lds)
        __builtin_amdgcn_global_load_lds(
            (const __attribute__((address_space(1))) void*)(Kh + (size_t)idx * HD + g * 8),
            (__attribute__((address_space(3))) void*)(KV + c * 8), 16, 0, 0);
#else
        *(short8*)(KV + c * 8) = *(const short8*)(Kh + (size_t)idx * HD + g * 8);
#endif
    }
    short8 vbuf[10];
#pragma unroll
    for (int i = 0; i < 10; ++i) {
        int c = i * 256 + t;
        int kk = c >> 3, dc = c & 7;
        int idx = min(max(kbase + kk, 0), S_LEN - 1);
        vbuf[i] = *(const short8*)(Vh + (size_t)idx * HD + dc * 8);
    }
    const int qi = q0 + w * 16 + lane16;
    const short* qp = Qh + (size_t)qi * HD;
    short8 bq0 = *(const short8*)(qp + quad * 8);
    short8 bq1 = *(const short8*)(qp + 32 + quad * 8);

    __syncthreads();

    f32x4 sc[NKT];
    const int s0 = (quad ^ (lane16 & 7)) * 8;
    const int s1 = ((quad + 4) ^ (lane16 & 7)) * 8;
#pragma unroll
    for (int kt = 0; kt < NKT; ++kt) {
        const short* kp = KV + (kt * 16 + lane16) * 64;
        short8 a0 = *(const short8*)(kp + s0);
        short8 a1 = *(const short8*)(kp + s1);
        f32x4 a = (f32x4){0.f, 0.f, 0.f, 0.f};
        a = __builtin_amdgcn_mfma_f32_16x16x32_bf16(a0, bq0, a, 0, 0, 0);
        a = __builtin_amdgcn_mfma_f32_16x16x32_bf16(a1, bq1, a, 0, 0, 0);
        sc[kt] = a;
    }

    const float scale = 0.125f;
    float m = -1e30f;
#pragma unroll
    for (int kt = 0; kt < NKT; ++kt) {
#pragma unroll
        for (int r = 0; r < 4; ++r) {
            int key = kbase + kt * 16 + quad * 4 + r;
            int d = qi - key;
            int ad = d < 0 ? -d : d;
            bool valid = (key >= 0) && (key < S_LEN) && (ad <= W);
            float s = valid ? sc[kt][r] * scale : -1e30f;
            sc[kt][r] = s;
            m = fmaxf(m, s);
        }
    }
    m = fmaxf(m, __shfl_xor(m, 16, 64));
    m = fmaxf(m, __shfl_xor(m, 32, 64));

    float lsum = 0.f;
#pragma unroll
    for (int kt = 0; kt < NKT; ++kt) {
#pragma unroll
        for (int r = 0; r < 4; ++r) {
            float p = __expf(sc[kt][r] - m);
            sc[kt][r] = p;
            lsum += p;
        }
    }
    lsum += __shfl_xor(lsum, 16, 64);
    lsum += __shfl_xor(lsum, 32, 64);
    const float rl = 1.f / fmaxf(lsum, 1e-30f);

    __syncthreads();
    {
        short(*Vt)[VSTR] = (short(*)[VSTR])KV;
#pragma unroll
        for (int i = 0; i < 10; ++i) {
            int c = i * 256 + t;
            int kk = c >> 3, dc = c & 7;
#pragma unroll
            for (int jj = 0; jj < 8; ++jj)
                Vt[dc * 8 + jj][kk] = vbuf[i][jj];
        }
    }
    __syncthreads();

    short(*Vt)[VSTR] = (short(*)[VSTR])KV;
    f32x4 oacc[4];
#pragma unroll
    for (int nt = 0; nt < 4; ++nt) oacc[nt] = (f32x4){0.f, 0.f, 0.f, 0.f};

#pragma unroll
    for (int kt = 0; kt < NKT; ++kt) {
        short4v pb = { f2bf(sc[kt][0]), f2bf(sc[kt][1]),
                       f2bf(sc[kt][2]), f2bf(sc[kt][3]) };
#pragma unroll
        for (int nt = 0; nt < 4; ++nt) {
            short4v va = *(const short4v*)(&Vt[nt * 16 + lane16][kt * 16 + quad * 4]);
            oacc[nt] = MFMA16(va, pb, oacc[nt]);
        }
    }

#pragma unroll
    for (int nt = 0; nt < 4; ++nt) {
        short4v ob = { f2bf(oacc[nt][0] * rl), f2bf(oacc[nt][1] * rl),
                       f2bf(oacc[nt][2] * rl), f2bf(oacc[nt][3] * rl) };
        *(short4v*)(attn_out + (size_t)qi * EMB + h * HD + nt * 16 + quad * 4) = ob;
    }
}

extern "C" void kernel_launch(void* const* d_in, const int* in_sizes, int n_in,
                              void* d_out, int out_size, void* d_ws, size_t ws_size,
                              hipStream_t stream) {
    const float* x    = (const float*)d_in[0];
    const float* Wqkv = (const float*)d_in[1];
    const float* bqkv = (const float*)d_in[2];
    const float* Wo   = (const float*)d_in[3];
    const float* bo   = (const float*)d_in[4];
    const int*   wptr = (const int*)d_in[5];

    float* out = (float*)d_out;

    short* xb     = (short*)d_ws;
    short* wqkvb  = xb     + (size_t)S_LEN * EMB;
    short* wob    = wqkvb  + (size_t)3 * EMB * EMB;
    short* qsplit = wob    + (size_t)EMB * EMB;
    short* attn   = qsplit + (size_t)3 * NH * S_LEN * HD;

    dim3 blk(256);
    convert_all<<<dim3((NX4 + NW4 + NO4) / 256), blk, 0, stream>>>(
        x, Wqkv, Wo, xb, wqkvb, wob);
    gemm_bt_bias<2><<<dim3(2304 / 128, S_LEN / 128), blk, 0, stream>>>(
        xb, wqkvb, bqkv, qsplit, S_LEN, 2304, EMB);
    attn_win<<<dim3(S_LEN / QT * NH), blk, 0, stream>>>(qsplit, wptr, attn);
    gemm_bt_bias<1><<<dim3(EMB / 128, S_LEN / 128), blk, 0, stream>>>(
        attn, wob, bo, out, S_LEN, EMB, EMB);
}

// Round 9
// 138.785 us; speedup vs baseline: 1.2952x; 1.0863x over previous
//
#include <hip/hip_runtime.h>

// SparseWindowedAttention: B=1, S=4096, E=768, H=12, hd=64, window=128
// Inputs fp32 (converted to bf16 in ws), output fp32. MFMA bf16, fp32 accum.
//
//   c0: fused fp32->bf16 convert (x, Wqkv, Wo)
//   k1: qkv GEMM (dbuf DMA) -> Q[12][4096][64] (pre-scaled by 0.125*log2e),
//       K[12][4096][64], V^T[12][64][4096]  (transpose done in epilogue)
//   k2: windowed attention: K DMA -> scores -> (WAR barrier, V^T DMA issued,
//       softmax VALU hides it) -> PV from same LDS buffer
//   k3: out = attn @ Wo^T + bo, 64x64-tile dbuf GEMM (768 blocks = 3/CU)

typedef __attribute__((ext_vector_type(8))) short short8;
typedef __attribute__((ext_vector_type(4))) short short4v;
typedef __attribute__((ext_vector_type(4))) float f32x4;

#define S_LEN 4096
#define EMB   768
#define NH    12
#define HD    64
#define QT    64      // queries per attention block (16 per wave)
#define WMAX  128
#define NKT   20      // key tiles of 16 covering [q0-128, q0+192)
#define QSCALE 0.18033688f   // 1/sqrt(64) * log2(e); softmax done base-2

#if defined(__HIP_DEVICE_COMPILE__)
#define MFMA16(a, b, c) __builtin_amdgcn_mfma_f32_16x16x16bf16_1k(a, b, c, 0, 0, 0)
#else
#define MFMA16(a, b, c) (c)
#endif

__device__ __forceinline__ short f2bf(float f) {
    union { unsigned int i; float f; } c;
    c.f = f;
    unsigned int i = c.i;
    unsigned int r = (i + 0x7FFFu + ((i >> 16) & 1u)) >> 16;
    return (short)(unsigned short)r;
}

// fused fp32->bf16: segments [x | Wqkv | Wo]
#define NX4  (S_LEN * EMB / 4)
#define NW4  (3 * EMB * EMB / 4)
#define NO4  (EMB * EMB / 4)
__global__ __launch_bounds__(256) void convert_all(
    const float* __restrict__ x, const float* __restrict__ wqkv,
    const float* __restrict__ wo, short* __restrict__ xb,
    short* __restrict__ wqkvb, short* __restrict__ wob)
{
    int i = blockIdx.x * 256 + threadIdx.x;
    const float* src; short* dst; int off;
    if (i < NX4)            { src = x;    dst = xb;    off = i; }
    else if (i < NX4 + NW4) { src = wqkv; dst = wqkvb; off = i - NX4; }
    else                    { src = wo;   dst = wob;   off = i - NX4 - NW4; }
    float4 v = ((const float4*)src)[off];
    short4v o = { f2bf(v.x), f2bf(v.y), f2bf(v.z), f2bf(v.w) };
    *(short4v*)(dst + (size_t)off * 4) = o;
}

// ---------------------------------------------------------------------------
// QKV GEMM: C = A·B^T + bias, 128x128 tile, BK=32, dbuf DMA pipeline.
// Epilogue: Q scaled by QSCALE (row-major), K row-major, V stored TRANSPOSED
// [h][d][row] via vectorized 8B stores (C-layout rows are consecutive).
// ---------------------------------------------------------------------------
__global__ __launch_bounds__(256) void gemm_qkv(
    const short* __restrict__ A, const short* __restrict__ B,
    const float* __restrict__ bias, short* __restrict__ Cv,
    int M, int N, int K)
{
    __shared__ __align__(16) short As[2][128 * 32];
    __shared__ __align__(16) short Bs[2][128 * 32];

    const int t = threadIdx.x;
    const int w = t >> 6, l = t & 63;
    const int quad = l >> 4, lane16 = l & 15;
    const int m0 = blockIdx.y * 128, n0 = blockIdx.x * 128;
    const int wm = (w >> 1) * 64, wn = (w & 1) * 64;

    f32x4 acc[4][4];
#pragma unroll
    for (int i = 0; i < 4; ++i)
#pragma unroll
        for (int j = 0; j < 4; ++j) acc[i][j] = (f32x4){0.f, 0.f, 0.f, 0.f};

    const int NKI = K >> 5;

    auto stage = [&](int ki, int b) {
#pragma unroll
        for (int i = 0; i < 2; ++i) {
            int c = i * 256 + t;
            int r = c >> 2, kc = c & 3;
#if defined(__HIP_DEVICE_COMPILE__) && __has_builtin(__builtin_amdgcn_global_load_lds)
            __builtin_amdgcn_global_load_lds(
                (const __attribute__((address_space(1))) void*)(A + (size_t)(m0 + r) * K + ki * 32 + kc * 8),
                (__attribute__((address_space(3))) void*)(As[b] + c * 8), 16, 0, 0);
            __builtin_amdgcn_global_load_lds(
                (const __attribute__((address_space(1))) void*)(B + (size_t)(n0 + r) * K + ki * 32 + kc * 8),
                (__attribute__((address_space(3))) void*)(Bs[b] + c * 8), 16, 0, 0);
#else
            *(short8*)(As[b] + c * 8) = *(const short8*)(A + (size_t)(m0 + r) * K + ki * 32 + kc * 8);
            *(short8*)(Bs[b] + c * 8) = *(const short8*)(B + (size_t)(n0 + r) * K + ki * 32 + kc * 8);
#endif
        }
    };

    stage(0, 0);
    for (int kb = 0; kb < NKI; ++kb) {
        const int cur = kb & 1;
        __syncthreads();
        if (kb + 1 < NKI) stage(kb + 1, cur ^ 1);

        short8 af[4], bfr[4];
#pragma unroll
        for (int mt = 0; mt < 4; ++mt)
            af[mt] = *(const short8*)(As[cur] + (wm + mt * 16 + lane16) * 32 + quad * 8);
#pragma unroll
        for (int nt = 0; nt < 4; ++nt)
            bfr[nt] = *(const short8*)(Bs[cur] + (wn + nt * 16 + lane16) * 32 + quad * 8);
#pragma unroll
        for (int mt = 0; mt < 4; ++mt)
#pragma unroll
            for (int nt = 0; nt < 4; ++nt)
                acc[mt][nt] = __builtin_amdgcn_mfma_f32_16x16x32_bf16(
                    af[mt], bfr[nt], acc[mt][nt], 0, 0, 0);
    }

#pragma unroll
    for (int nt = 0; nt < 4; ++nt) {
        int col = n0 + wn + nt * 16 + lane16;
        float bv = bias[col];
        int h = col / 192;
        int rem = col - h * 192;
        int ty = rem >> 6, d = rem & 63;
        if (ty == 2) {
            // V^T[h][d][row]: 4 consecutive rows per acc reg -> 8B store
            short* vt = Cv + ((size_t)2 * NH * S_LEN) * HD + ((size_t)h * HD + d) * S_LEN;
#pragma unroll
            for (int mt = 0; mt < 4; ++mt) {
                int row0 = m0 + wm + mt * 16 + quad * 4;
                short4v o = { f2bf(acc[mt][nt][0] + bv), f2bf(acc[mt][nt][1] + bv),
                              f2bf(acc[mt][nt][2] + bv), f2bf(acc[mt][nt][3] + bv) };
                *(short4v*)(vt + row0) = o;
            }
        } else {
            float s = (ty == 0) ? QSCALE : 1.f;
            short* dst = Cv + ((size_t)ty * NH + h) * S_LEN * HD + d;
#pragma unroll
            for (int mt = 0; mt < 4; ++mt) {
#pragma unroll
                for (int r = 0; r < 4; ++r) {
                    int row = m0 + wm + mt * 16 + quad * 4 + r;
                    dst[(size_t)row * HD] = f2bf((acc[mt][nt][r] + bv) * s);
                }
            }
        }
    }
}

// ---------------------------------------------------------------------------
// Windowed attention. Q pre-scaled -> scores are base-2 logits.
// One 40960B LDS buffer: K (swizzled) for scores, then V^T (swizzled) for PV;
// V^T DMA issued right after the WAR barrier, hidden under softmax VALU.
// ---------------------------------------------------------------------------
__global__ __launch_bounds__(256, 3) void attn_win(
    const short* __restrict__ qsplit, const int* __restrict__ wptr,
    short* __restrict__ attn_out)
{
    __shared__ __align__(16) short KS[320 * 64];   // 40960 B

    const int t = threadIdx.x;
    const int w = t >> 6, l = t & 63;
    const int quad = l >> 4, lane16 = l & 15;

    const int id = blockIdx.x;
    const int xcd = id & 7, j = id >> 3;
    const int h = j >> 3;
    const int q0 = ((xcd << 3) + (j & 7)) * QT;
    const int W = *wptr;
    const int kbase = q0 - WMAX;

    const short* Qh  = qsplit + (size_t)h * S_LEN * HD;
    const short* Kh  = qsplit + (size_t)(NH + h) * S_LEN * HD;
    const short* VtG = qsplit + (size_t)2 * NH * S_LEN * HD + (size_t)h * HD * S_LEN;

    // (a) K -> LDS DMA, source-XOR swizzle: slot gs holds global group gs^(r&7)
#pragma unroll
    for (int i = 0; i < 10; ++i) {
        int c = i * 256 + t;
        int r = c >> 3, gs = c & 7;
        int g = gs ^ (r & 7);
        int idx = min(max(kbase + r, 0), S_LEN - 1);
#if defined(__HIP_DEVICE_COMPILE__) && __has_builtin(__builtin_amdgcn_global_load_lds)
        __builtin_amdgcn_global_load_lds(
            (const __attribute__((address_space(1))) void*)(Kh + (size_t)idx * HD + g * 8),
            (__attribute__((address_space(3))) void*)(KS + c * 8), 16, 0, 0);
#else
        *(short8*)(KS + c * 8) = *(const short8*)(Kh + (size_t)idx * HD + g * 8);
#endif
    }
    // Q as B-operand: B[n=q=lane16][k=dim=quad*8+j]
    const int qi = q0 + w * 16 + lane16;
    const short* qp = Qh + (size_t)qi * HD;
    short8 bq0 = *(const short8*)(qp + quad * 8);
    short8 bq1 = *(const short8*)(qp + 32 + quad * 8);

    __syncthreads();   // K resident

    // (b) scores: St[key][q], A=K from LDS (swizzled slots), B=Q
    f32x4 sc[NKT];
    const int d7 = lane16 & 7;
    const int s0 = (quad ^ d7) * 8;
    const int s1 = ((quad + 4) ^ d7) * 8;
#pragma unroll
    for (int kt = 0; kt < NKT; ++kt) {
        const short* kp = KS + (kt * 16 + lane16) * 64;
        short8 a0 = *(const short8*)(kp + s0);
        short8 a1 = *(const short8*)(kp + s1);
        f32x4 a = (f32x4){0.f, 0.f, 0.f, 0.f};
        a = __builtin_amdgcn_mfma_f32_16x16x32_bf16(a0, bq0, a, 0, 0, 0);
        a = __builtin_amdgcn_mfma_f32_16x16x32_bf16(a1, bq1, a, 0, 0, 0);
        sc[kt] = a;
    }

    __syncthreads();   // WAR: all K reads done; KS now free for V^T

    // (c) V^T -> same LDS via DMA (row d = 320 keys = 40 chunks, swizzled in
    //     8-chunk groups); latency hidden under the softmax below.
#pragma unroll
    for (int i = 0; i < 10; ++i) {
        int c = i * 256 + t;
        int d = c / 40;
        int slot = c - d * 40;
        int sg = slot >> 3, s = slot & 7;
        int g = s ^ (d & 7);
        int key0 = kbase + sg * 64 + g * 8;
        key0 = min(max(key0, 0), S_LEN - 8);   // chunk-aligned clamp (masked keys * P=0)
#if defined(__HIP_DEVICE_COMPILE__) && __has_builtin(__builtin_amdgcn_global_load_lds)
        __builtin_amdgcn_global_load_lds(
            (const __attribute__((address_space(1))) void*)(VtG + (size_t)d * S_LEN + key0),
            (__attribute__((address_space(3))) void*)(KS + c * 8), 16, 0, 0);
#else
        *(short8*)(KS + c * 8) = *(const short8*)(VtG + (size_t)d * S_LEN + key0);
#endif
    }

    // softmax (base-2, Q pre-scaled): mask is select-only
    float m = -1e30f;
#pragma unroll
    for (int kt = 0; kt < NKT; ++kt) {
#pragma unroll
        for (int r = 0; r < 4; ++r) {
            int key = kbase + kt * 16 + quad * 4 + r;
            int dd = qi - key;
            int ad = dd < 0 ? -dd : dd;
            bool valid = ((unsigned)key < S_LEN) && (ad <= W);
            float s = valid ? sc[kt][r] : -1e30f;
            sc[kt][r] = s;
            m = fmaxf(m, s);
        }
    }
    m = fmaxf(m, __shfl_xor(m, 16, 64));
    m = fmaxf(m, __shfl_xor(m, 32, 64));

    float lsum = 0.f;
#pragma unroll
    for (int kt = 0; kt < NKT; ++kt) {
#pragma unroll
        for (int r = 0; r < 4; ++r) {
            float p = exp2f(sc[kt][r] - m);
            sc[kt][r] = p;
            lsum += p;
        }
    }
    lsum += __shfl_xor(lsum, 16, 64);
    lsum += __shfl_xor(lsum, 32, 64);
    const float rl = 1.f / fmaxf(lsum, 1e-30f);

    __syncthreads();   // V^T resident (drains DMA vmcnt)

    // (d) PV: O^T[d][q] += V^T[d][k]·P[k][q]; P (C-layout) is the B-frag
    f32x4 oacc[4];
#pragma unroll
    for (int nt = 0; nt < 4; ++nt) oacc[nt] = (f32x4){0.f, 0.f, 0.f, 0.f};

#pragma unroll
    for (int kt = 0; kt < NKT; ++kt) {
        short4v pb = { f2bf(sc[kt][0]), f2bf(sc[kt][1]),
                       f2bf(sc[kt][2]), f2bf(sc[kt][3]) };
        int G = kt * 2 + (quad >> 1);
        int off = (G >> 3) * 64 + ((G & 7) ^ d7) * 8 + (quad & 1) * 4;
#pragma unroll
        for (int nt = 0; nt < 4; ++nt) {
            short4v va = *(const short4v*)(KS + (nt * 16 + lane16) * 320 + off);
            oacc[nt] = MFMA16(va, pb, oacc[nt]);
        }
    }

    // normalize + store: O^T row=d=quad*4+r, col=q=lane16 -> 8B stores
#pragma unroll
    for (int nt = 0; nt < 4; ++nt) {
        short4v ob = { f2bf(oacc[nt][0] * rl), f2bf(oacc[nt][1] * rl),
                       f2bf(oacc[nt][2] * rl), f2bf(oacc[nt][3] * rl) };
        *(short4v*)(attn_out + (size_t)qi * EMB + h * HD + nt * 16 + quad * 4) = ob;
    }
}

// ---------------------------------------------------------------------------
// Output projection GEMM: 64x64 tile, BK=64, dbuf DMA w/ source-XOR swizzle.
// Grid (12, 64) = 768 blocks = 3/CU even. fp32 output.
// ---------------------------------------------------------------------------
__global__ __launch_bounds__(256) void gemm_out64(
    const short* __restrict__ A, const short* __restrict__ B,
    const float* __restrict__ bias, float* __restrict__ C,
    int M, int N, int K)
{
    __shared__ __align__(16) short As[2][64 * 64];
    __shared__ __align__(16) short Bs[2][64 * 64];

    const int t = threadIdx.x;
    const int w = t >> 6, l = t & 63;
    const int quad = l >> 4, lane16 = l & 15;
    const int m0 = blockIdx.y * 64, n0 = blockIdx.x * 64;
    const int wm = (w >> 1) * 32, wn = (w & 1) * 32;

    f32x4 acc[2][2];
#pragma unroll
    for (int i = 0; i < 2; ++i)
#pragma unroll
        for (int j = 0; j < 2; ++j) acc[i][j] = (f32x4){0.f, 0.f, 0.f, 0.f};

    const int NKI = K >> 6;   // 12

    auto stage = [&](int ki, int b) {
#pragma unroll
        for (int i = 0; i < 2; ++i) {
            int c = i * 256 + t;          // chunk 0..511 per matrix
            int r = c >> 3, kc = c & 7;
            int g = kc ^ (r & 7);         // source group (slot kc holds it)
#if defined(__HIP_DEVICE_COMPILE__) && __has_builtin(__builtin_amdgcn_global_load_lds)
            __builtin_amdgcn_global_load_lds(
                (const __attribute__((address_space(1))) void*)(A + (size_t)(m0 + r) * K + ki * 64 + g * 8),
                (__attribute__((address_space(3))) void*)(As[b] + c * 8), 16, 0, 0);
            __builtin_amdgcn_global_load_lds(
                (const __attribute__((address_space(1))) void*)(B + (size_t)(n0 + r) * K + ki * 64 + g * 8),
                (__attribute__((address_space(3))) void*)(Bs[b] + c * 8), 16, 0, 0);
#else
            *(short8*)(As[b] + c * 8) = *(const short8*)(A + (size_t)(m0 + r) * K + ki * 64 + g * 8);
            *(short8*)(Bs[b] + c * 8) = *(const short8*)(B + (size_t)(n0 + r) * K + ki * 64 + g * 8);
#endif
        }
    };

    stage(0, 0);
    for (int kb = 0; kb < NKI; ++kb) {
        const int cur = kb & 1;
        __syncthreads();
        if (kb + 1 < NKI) stage(kb + 1, cur ^ 1);

#pragma unroll
        for (int ks = 0; ks < 2; ++ks) {
            short8 af[2], bfr[2];
#pragma unroll
            for (int mt = 0; mt < 2; ++mt) {
                int row = wm + mt * 16 + lane16;
                int slot = (ks * 4 + quad) ^ (row & 7);
                af[mt] = *(const short8*)(As[cur] + row * 64 + slot * 8);
            }
#pragma unroll
            for (int nt = 0; nt < 2; ++nt) {
                int row = wn + nt * 16 + lane16;
                int slot = (ks * 4 + quad) ^ (row & 7);
                bfr[nt] = *(const short8*)(Bs[cur] + row * 64 + slot * 8);
            }
#pragma unroll
            for (int mt = 0; mt < 2; ++mt)
#pragma unroll
                for (int nt = 0; nt < 2; ++nt)
                    acc[mt][nt] = __builtin_amdgcn_mfma_f32_16x16x32_bf16(
                        af[mt], bfr[nt], acc[mt][nt], 0, 0, 0);
        }
    }

#pragma unroll
    for (int nt = 0; nt < 2; ++nt) {
        int col = n0 + wn + nt * 16 + lane16;
        float bv = bias[col];
#pragma unroll
        for (int mt = 0; mt < 2; ++mt) {
#pragma unroll
            for (int r = 0; r < 4; ++r) {
                int row = m0 + wm + mt * 16 + quad * 4 + r;
                C[(size_t)row * N + col] = acc[mt][nt][r] + bv;
            }
        }
    }
}

extern "C" void kernel_launch(void* const* d_in, const int* in_sizes, int n_in,
                              void* d_out, int out_size, void* d_ws, size_t ws_size,
                              hipStream_t stream) {
    const float* x    = (const float*)d_in[0];
    const float* Wqkv = (const float*)d_in[1];
    const float* bqkv = (const float*)d_in[2];
    const float* Wo   = (const float*)d_in[3];
    const float* bo   = (const float*)d_in[4];
    const int*   wptr = (const int*)d_in[5];

    float* out = (float*)d_out;

    short* xb     = (short*)d_ws;
    short* wqkvb  = xb     + (size_t)S_LEN * EMB;
    short* wob    = wqkvb  + (size_t)3 * EMB * EMB;
    short* qsplit = wob    + (size_t)EMB * EMB;          // Q|K row-major, V^T
    short* attn   = qsplit + (size_t)3 * NH * S_LEN * HD;

    dim3 blk(256);
    convert_all<<<dim3((NX4 + NW4 + NO4) / 256), blk, 0, stream>>>(
        x, Wqkv, Wo, xb, wqkvb, wob);
    gemm_qkv<<<dim3(2304 / 128, S_LEN / 128), blk, 0, stream>>>(
        xb, wqkvb, bqkv, qsplit, S_LEN, 2304, EMB);
    attn_win<<<dim3(S_LEN / QT * NH), blk, 0, stream>>>(qsplit, wptr, attn);
    gemm_out64<<<dim3(EMB / 64, S_LEN / 64), blk, 0, stream>>>(
        attn, wob, bo, out, S_LEN, EMB, EMB);
}

// Round 10
// 137.551 us; speedup vs baseline: 1.3068x; 1.0090x over previous
//
#include <hip/hip_runtime.h>

// SparseWindowedAttention: B=1, S=4096, E=768, H=12, hd=64, window=128
// Inputs fp32 (converted to bf16 in ws), output fp32. MFMA bf16, fp32 accum.
//
//   c0: fused fp32->bf16 convert (x, Wqkv, Wo)
//   k1: qkv GEMM, 128x96 tile (768 blocks = 3/CU exact), dbuf DMA ->
//       Q[12][4096][64] (pre-scaled 0.125*log2e), K[12][4096][64], V^T[12][64][4096]
//   k2: windowed attention (unchanged from R9)
//   k3: out = attn @ Wo^T + bo, 64x64-tile dbuf GEMM (768 blocks)

typedef __attribute__((ext_vector_type(8))) short short8;
typedef __attribute__((ext_vector_type(4))) short short4v;
typedef __attribute__((ext_vector_type(4))) float f32x4;

#define S_LEN 4096
#define EMB   768
#define NH    12
#define HD    64
#define QT    64      // queries per attention block (16 per wave)
#define WMAX  128
#define NKT   20      // key tiles of 16 covering [q0-128, q0+192)
#define QSCALE 0.18033688f   // 1/sqrt(64) * log2(e); softmax done base-2

#if defined(__HIP_DEVICE_COMPILE__)
#define MFMA16(a, b, c) __builtin_amdgcn_mfma_f32_16x16x16bf16_1k(a, b, c, 0, 0, 0)
#else
#define MFMA16(a, b, c) (c)
#endif

__device__ __forceinline__ short f2bf(float f) {
    union { unsigned int i; float f; } c;
    c.f = f;
    unsigned int i = c.i;
    unsigned int r = (i + 0x7FFFu + ((i >> 16) & 1u)) >> 16;
    return (short)(unsigned short)r;
}

// fused fp32->bf16: segments [x | Wqkv | Wo]
#define NX4  (S_LEN * EMB / 4)
#define NW4  (3 * EMB * EMB / 4)
#define NO4  (EMB * EMB / 4)
__global__ __launch_bounds__(256) void convert_all(
    const float* __restrict__ x, const float* __restrict__ wqkv,
    const float* __restrict__ wo, short* __restrict__ xb,
    short* __restrict__ wqkvb, short* __restrict__ wob)
{
    int i = blockIdx.x * 256 + threadIdx.x;
    const float* src; short* dst; int off;
    if (i < NX4)            { src = x;    dst = xb;    off = i; }
    else if (i < NX4 + NW4) { src = wqkv; dst = wqkvb; off = i - NX4; }
    else                    { src = wo;   dst = wob;   off = i - NX4 - NW4; }
    float4 v = ((const float4*)src)[off];
    short4v o = { f2bf(v.x), f2bf(v.y), f2bf(v.z), f2bf(v.w) };
    *(short4v*)(dst + (size_t)off * 4) = o;
}

// ---------------------------------------------------------------------------
// QKV GEMM: C = A·B^T + bias, 128(M)x96(N) tile, BK=32, dbuf DMA pipeline.
// Grid (24, 32) = 768 blocks = exactly 3/CU (no dispatch tail).
// Wave w: rows (w>>1)*64, cols (w&1)*48 -> acc[4][3] (48 VGPRs).
// Staging: 896 chunks (A 512, B 384), 4 wave-uniform passes.
// Epilogue: Q scaled by QSCALE, K row-major, V^T[h][d][row] 8B stores.
// ---------------------------------------------------------------------------
__global__ __launch_bounds__(256) void gemm_qkv(
    const short* __restrict__ A, const short* __restrict__ B,
    const float* __restrict__ bias, short* __restrict__ Cv,
    int M, int N, int K)
{
    __shared__ __align__(16) short As[2][128 * 32];
    __shared__ __align__(16) short Bs[2][96 * 32];

    const int t = threadIdx.x;
    const int w = t >> 6, l = t & 63;
    const int quad = l >> 4, lane16 = l & 15;
    const int m0 = blockIdx.y * 128, n0 = blockIdx.x * 96;
    const int wm = (w >> 1) * 64, wn = (w & 1) * 48;

    f32x4 acc[4][3];
#pragma unroll
    for (int i = 0; i < 4; ++i)
#pragma unroll
        for (int j = 0; j < 3; ++j) acc[i][j] = (f32x4){0.f, 0.f, 0.f, 0.f};

    const int NKI = K >> 5;   // 24

    auto stage = [&](int ki, int b) {
#pragma unroll
        for (int i = 0; i < 4; ++i) {
            int c = i * 256 + t;              // 0..1023; 896 used
            if (c < 512) {                    // A chunk: row r, col-group kc
                int r = c >> 2, kc = c & 3;
#if defined(__HIP_DEVICE_COMPILE__) && __has_builtin(__builtin_amdgcn_global_load_lds)
                __builtin_amdgcn_global_load_lds(
                    (const __attribute__((address_space(1))) void*)(A + (size_t)(m0 + r) * K + ki * 32 + kc * 8),
                    (__attribute__((address_space(3))) void*)(As[b] + c * 8), 16, 0, 0);
#else
                *(short8*)(As[b] + c * 8) = *(const short8*)(A + (size_t)(m0 + r) * K + ki * 32 + kc * 8);
#endif
            } else if (c < 896) {             // B chunk
                int cb = c - 512;
                int r = cb >> 2, kc = cb & 3;
#if defined(__HIP_DEVICE_COMPILE__) && __has_builtin(__builtin_amdgcn_global_load_lds)
                __builtin_amdgcn_global_load_lds(
                    (const __attribute__((address_space(1))) void*)(B + (size_t)(n0 + r) * K + ki * 32 + kc * 8),
                    (__attribute__((address_space(3))) void*)(Bs[b] + cb * 8), 16, 0, 0);
#else
                *(short8*)(Bs[b] + cb * 8) = *(const short8*)(B + (size_t)(n0 + r) * K + ki * 32 + kc * 8);
#endif
            }
        }
    };

    stage(0, 0);
    for (int kb = 0; kb < NKI; ++kb) {
        const int cur = kb & 1;
        __syncthreads();                      // buf[cur] DMA drained; prev reads done
        if (kb + 1 < NKI) stage(kb + 1, cur ^ 1);

        short8 af[4], bfr[3];
#pragma unroll
        for (int mt = 0; mt < 4; ++mt)
            af[mt] = *(const short8*)(As[cur] + (wm + mt * 16 + lane16) * 32 + quad * 8);
#pragma unroll
        for (int nt = 0; nt < 3; ++nt)
            bfr[nt] = *(const short8*)(Bs[cur] + (wn + nt * 16 + lane16) * 32 + quad * 8);
#pragma unroll
        for (int mt = 0; mt < 4; ++mt)
#pragma unroll
            for (int nt = 0; nt < 3; ++nt)
                acc[mt][nt] = __builtin_amdgcn_mfma_f32_16x16x32_bf16(
                    af[mt], bfr[nt], acc[mt][nt], 0, 0, 0);
    }

#pragma unroll
    for (int nt = 0; nt < 3; ++nt) {
        int col = n0 + wn + nt * 16 + lane16;
        float bv = bias[col];
        int h = col / 192;
        int rem = col - h * 192;
        int ty = rem >> 6, d = rem & 63;
        if (ty == 2) {
            // V^T[h][d][row]: 4 consecutive rows per acc reg -> 8B store
            short* vt = Cv + ((size_t)2 * NH * S_LEN) * HD + ((size_t)h * HD + d) * S_LEN;
#pragma unroll
            for (int mt = 0; mt < 4; ++mt) {
                int row0 = m0 + wm + mt * 16 + quad * 4;
                short4v o = { f2bf(acc[mt][nt][0] + bv), f2bf(acc[mt][nt][1] + bv),
                              f2bf(acc[mt][nt][2] + bv), f2bf(acc[mt][nt][3] + bv) };
                *(short4v*)(vt + row0) = o;
            }
        } else {
            float s = (ty == 0) ? QSCALE : 1.f;
            short* dst = Cv + ((size_t)ty * NH + h) * S_LEN * HD + d;
#pragma unroll
            for (int mt = 0; mt < 4; ++mt) {
#pragma unroll
                for (int r = 0; r < 4; ++r) {
                    int row = m0 + wm + mt * 16 + quad * 4 + r;
                    dst[(size_t)row * HD] = f2bf((acc[mt][nt][r] + bv) * s);
                }
            }
        }
    }
}

// ---------------------------------------------------------------------------
// Windowed attention (unchanged from R9). Q pre-scaled -> base-2 softmax.
// One 40960B LDS buffer: K (swizzled) for scores, then V^T for PV; V^T DMA
// issued after the WAR barrier, hidden under softmax VALU.
// ---------------------------------------------------------------------------
__global__ __launch_bounds__(256, 3) void attn_win(
    const short* __restrict__ qsplit, const int* __restrict__ wptr,
    short* __restrict__ attn_out)
{
    __shared__ __align__(16) short KS[320 * 64];   // 40960 B

    const int t = threadIdx.x;
    const int w = t >> 6, l = t & 63;
    const int quad = l >> 4, lane16 = l & 15;

    const int id = blockIdx.x;
    const int xcd = id & 7, j = id >> 3;
    const int h = j >> 3;
    const int q0 = ((xcd << 3) + (j & 7)) * QT;
    const int W = *wptr;
    const int kbase = q0 - WMAX;

    const short* Qh  = qsplit + (size_t)h * S_LEN * HD;
    const short* Kh  = qsplit + (size_t)(NH + h) * S_LEN * HD;
    const short* VtG = qsplit + (size_t)2 * NH * S_LEN * HD + (size_t)h * HD * S_LEN;

#pragma unroll
    for (int i = 0; i < 10; ++i) {
        int c = i * 256 + t;
        int r = c >> 3, gs = c & 7;
        int g = gs ^ (r & 7);
        int idx = min(max(kbase + r, 0), S_LEN - 1);
#if defined(__HIP_DEVICE_COMPILE__) && __has_builtin(__builtin_amdgcn_global_load_lds)
        __builtin_amdgcn_global_load_lds(
            (const __attribute__((address_space(1))) void*)(Kh + (size_t)idx * HD + g * 8),
            (__attribute__((address_space(3))) void*)(KS + c * 8), 16, 0, 0);
#else
        *(short8*)(KS + c * 8) = *(const short8*)(Kh + (size_t)idx * HD + g * 8);
#endif
    }
    const int qi = q0 + w * 16 + lane16;
    const short* qp = Qh + (size_t)qi * HD;
    short8 bq0 = *(const short8*)(qp + quad * 8);
    short8 bq1 = *(const short8*)(qp + 32 + quad * 8);

    __syncthreads();   // K resident

    f32x4 sc[NKT];
    const int d7 = lane16 & 7;
    const int s0 = (quad ^ d7) * 8;
    const int s1 = ((quad + 4) ^ d7) * 8;
#pragma unroll
    for (int kt = 0; kt < NKT; ++kt) {
        const short* kp = KS + (kt * 16 + lane16) * 64;
        short8 a0 = *(const short8*)(kp + s0);
        short8 a1 = *(const short8*)(kp + s1);
        f32x4 a = (f32x4){0.f, 0.f, 0.f, 0.f};
        a = __builtin_amdgcn_mfma_f32_16x16x32_bf16(a0, bq0, a, 0, 0, 0);
        a = __builtin_amdgcn_mfma_f32_16x16x32_bf16(a1, bq1, a, 0, 0, 0);
        sc[kt] = a;
    }

    __syncthreads();   // WAR: all K reads done; KS free for V^T

#pragma unroll
    for (int i = 0; i < 10; ++i) {
        int c = i * 256 + t;
        int d = c / 40;
        int slot = c - d * 40;
        int sg = slot >> 3, s = slot & 7;
        int g = s ^ (d & 7);
        int key0 = kbase + sg * 64 + g * 8;
        key0 = min(max(key0, 0), S_LEN - 8);   // chunk-aligned clamp (masked keys * P=0)
#if defined(__HIP_DEVICE_COMPILE__) && __has_builtin(__builtin_amdgcn_global_load_lds)
        __builtin_amdgcn_global_load_lds(
            (const __attribute__((address_space(1))) void*)(VtG + (size_t)d * S_LEN + key0),
            (__attribute__((address_space(3))) void*)(KS + c * 8), 16, 0, 0);
#else
        *(short8*)(KS + c * 8) = *(const short8*)(VtG + (size_t)d * S_LEN + key0);
#endif
    }

    float m = -1e30f;
#pragma unroll
    for (int kt = 0; kt < NKT; ++kt) {
#pragma unroll
        for (int r = 0; r < 4; ++r) {
            int key = kbase + kt * 16 + quad * 4 + r;
            int dd = qi - key;
            int ad = dd < 0 ? -dd : dd;
            bool valid = ((unsigned)key < S_LEN) && (ad <= W);
            float s = valid ? sc[kt][r] : -1e30f;
            sc[kt][r] = s;
            m = fmaxf(m, s);
        }
    }
    m = fmaxf(m, __shfl_xor(m, 16, 64));
    m = fmaxf(m, __shfl_xor(m, 32, 64));

    float lsum = 0.f;
#pragma unroll
    for (int kt = 0; kt < NKT; ++kt) {
#pragma unroll
        for (int r = 0; r < 4; ++r) {
            float p = exp2f(sc[kt][r] - m);
            sc[kt][r] = p;
            lsum += p;
        }
    }
    lsum += __shfl_xor(lsum, 16, 64);
    lsum += __shfl_xor(lsum, 32, 64);
    const float rl = 1.f / fmaxf(lsum, 1e-30f);

    __syncthreads();   // V^T resident

    f32x4 oacc[4];
#pragma unroll
    for (int nt = 0; nt < 4; ++nt) oacc[nt] = (f32x4){0.f, 0.f, 0.f, 0.f};

#pragma unroll
    for (int kt = 0; kt < NKT; ++kt) {
        short4v pb = { f2bf(sc[kt][0]), f2bf(sc[kt][1]),
                       f2bf(sc[kt][2]), f2bf(sc[kt][3]) };
        int G = kt * 2 + (quad >> 1);
        int off = (G >> 3) * 64 + ((G & 7) ^ d7) * 8 + (quad & 1) * 4;
#pragma unroll
        for (int nt = 0; nt < 4; ++nt) {
            short4v va = *(const short4v*)(KS + (nt * 16 + lane16) * 320 + off);
            oacc[nt] = MFMA16(va, pb, oacc[nt]);
        }
    }

#pragma unroll
    for (int nt = 0; nt < 4; ++nt) {
        short4v ob = { f2bf(oacc[nt][0] * rl), f2bf(oacc[nt][1] * rl),
                       f2bf(oacc[nt][2] * rl), f2bf(oacc[nt][3] * rl) };
        *(short4v*)(attn_out + (size_t)qi * EMB + h * HD + nt * 16 + quad * 4) = ob;
    }
}

// ---------------------------------------------------------------------------
// Output projection GEMM: 64x64 tile, BK=64, dbuf DMA w/ source-XOR swizzle.
// Grid (12, 64) = 768 blocks = 3/CU even. fp32 output. (unchanged from R9)
// ---------------------------------------------------------------------------
__global__ __launch_bounds__(256) void gemm_out64(
    const short* __restrict__ A, const short* __restrict__ B,
    const float* __restrict__ bias, float* __restrict__ C,
    int M, int N, int K)
{
    __shared__ __align__(16) short As[2][64 * 64];
    __shared__ __align__(16) short Bs[2][64 * 64];

    const int t = threadIdx.x;
    const int w = t >> 6, l = t & 63;
    const int quad = l >> 4, lane16 = l & 15;
    const int m0 = blockIdx.y * 64, n0 = blockIdx.x * 64;
    const int wm = (w >> 1) * 32, wn = (w & 1) * 32;

    f32x4 acc[2][2];
#pragma unroll
    for (int i = 0; i < 2; ++i)
#pragma unroll
        for (int j = 0; j < 2; ++j) acc[i][j] = (f32x4){0.f, 0.f, 0.f, 0.f};

    const int NKI = K >> 6;   // 12

    auto stage = [&](int ki, int b) {
#pragma unroll
        for (int i = 0; i < 2; ++i) {
            int c = i * 256 + t;
            int r = c >> 3, kc = c & 7;
            int g = kc ^ (r & 7);
#if defined(__HIP_DEVICE_COMPILE__) && __has_builtin(__builtin_amdgcn_global_load_lds)
            __builtin_amdgcn_global_load_lds(
                (const __attribute__((address_space(1))) void*)(A + (size_t)(m0 + r) * K + ki * 64 + g * 8),
                (__attribute__((address_space(3))) void*)(As[b] + c * 8), 16, 0, 0);
            __builtin_amdgcn_global_load_lds(
                (const __attribute__((address_space(1))) void*)(B + (size_t)(n0 + r) * K + ki * 64 + g * 8),
                (__attribute__((address_space(3))) void*)(Bs[b] + c * 8), 16, 0, 0);
#else
            *(short8*)(As[b] + c * 8) = *(const short8*)(A + (size_t)(m0 + r) * K + ki * 64 + g * 8);
            *(short8*)(Bs[b] + c * 8) = *(const short8*)(B + (size_t)(n0 + r) * K + ki * 64 + g * 8);
#endif
        }
    };

    stage(0, 0);
    for (int kb = 0; kb < NKI; ++kb) {
        const int cur = kb & 1;
        __syncthreads();
        if (kb + 1 < NKI) stage(kb + 1, cur ^ 1);

#pragma unroll
        for (int ks = 0; ks < 2; ++ks) {
            short8 af[2], bfr[2];
#pragma unroll
            for (int mt = 0; mt < 2; ++mt) {
                int row = wm + mt * 16 + lane16;
                int slot = (ks * 4 + quad) ^ (row & 7);
                af[mt] = *(const short8*)(As[cur] + row * 64 + slot * 8);
            }
#pragma unroll
            for (int nt = 0; nt < 2; ++nt) {
                int row = wn + nt * 16 + lane16;
                int slot = (ks * 4 + quad) ^ (row & 7);
                bfr[nt] = *(const short8*)(Bs[cur] + row * 64 + slot * 8);
            }
#pragma unroll
            for (int mt = 0; mt < 2; ++mt)
#pragma unroll
                for (int nt = 0; nt < 2; ++nt)
                    acc[mt][nt] = __builtin_amdgcn_mfma_f32_16x16x32_bf16(
                        af[mt], bfr[nt], acc[mt][nt], 0, 0, 0);
        }
    }

#pragma unroll
    for (int nt = 0; nt < 2; ++nt) {
        int col = n0 + wn + nt * 16 + lane16;
        float bv = bias[col];
#pragma unroll
        for (int mt = 0; mt < 2; ++mt) {
#pragma unroll
            for (int r = 0; r < 4; ++r) {
                int row = m0 + wm + mt * 16 + quad * 4 + r;
                C[(size_t)row * N + col] = acc[mt][nt][r] + bv;
            }
        }
    }
}

extern "C" void kernel_launch(void* const* d_in, const int* in_sizes, int n_in,
                              void* d_out, int out_size, void* d_ws, size_t ws_size,
                              hipStream_t stream) {
    const float* x    = (const float*)d_in[0];
    const float* Wqkv = (const float*)d_in[1];
    const float* bqkv = (const float*)d_in[2];
    const float* Wo   = (const float*)d_in[3];
    const float* bo   = (const float*)d_in[4];
    const int*   wptr = (const int*)d_in[5];

    float* out = (float*)d_out;

    short* xb     = (short*)d_ws;
    short* wqkvb  = xb     + (size_t)S_LEN * EMB;
    short* wob    = wqkvb  + (size_t)3 * EMB * EMB;
    short* qsplit = wob    + (size_t)EMB * EMB;          // Q|K row-major, V^T
    short* attn   = qsplit + (size_t)3 * NH * S_LEN * HD;

    dim3 blk(256);
    convert_all<<<dim3((NX4 + NW4 + NO4) / 256), blk, 0, stream>>>(
        x, Wqkv, Wo, xb, wqkvb, wob);
    gemm_qkv<<<dim3(2304 / 96, S_LEN / 128), blk, 0, stream>>>(
        xb, wqkvb, bqkv, qsplit, S_LEN, 2304, EMB);
    attn_win<<<dim3(S_LEN / QT * NH), blk, 0, stream>>>(qsplit, wptr, attn);
    gemm_out64<<<dim3(EMB / 64, S_LEN / 64), blk, 0, stream>>>(
        attn, wob, bo, out, S_LEN, EMB, EMB);
}

// Round 11
// 134.219 us; speedup vs baseline: 1.3392x; 1.0248x over previous
//
#include <hip/hip_runtime.h>

// SparseWindowedAttention: B=1, S=4096, E=768, H=12, hd=64, window=128
// Inputs fp32 (converted to bf16 in ws), output fp32. MFMA bf16, fp32 accum.
//
//   c0: fused fp32->bf16 convert (x, Wqkv, Wo)
//   k1: qkv GEMM 128x96 (768 blocks = 3/CU), dbuf DMA; epilogue: V^T direct
//       8B stores, Q/K via LDS-round-trip -> 16B/lane coalesced stores
//   k2: windowed attention (unchanged from R9/R10)
//   k3: out = attn @ Wo^T + bo, 64x64 dbuf GEMM; LDS-round-trip fp32 epilogue

typedef __attribute__((ext_vector_type(8))) short short8;
typedef __attribute__((ext_vector_type(4))) short short4v;
typedef __attribute__((ext_vector_type(4))) float f32x4;

#define S_LEN 4096
#define EMB   768
#define NH    12
#define HD    64
#define QT    64
#define WMAX  128
#define NKT   20
#define QSCALE 0.18033688f   // 1/sqrt(64) * log2(e); softmax base-2

#if defined(__HIP_DEVICE_COMPILE__)
#define MFMA16(a, b, c) __builtin_amdgcn_mfma_f32_16x16x16bf16_1k(a, b, c, 0, 0, 0)
#else
#define MFMA16(a, b, c) (c)
#endif

__device__ __forceinline__ short f2bf(float f) {
    union { unsigned int i; float f; } c;
    c.f = f;
    unsigned int i = c.i;
    unsigned int r = (i + 0x7FFFu + ((i >> 16) & 1u)) >> 16;
    return (short)(unsigned short)r;
}

// fused fp32->bf16: segments [x | Wqkv | Wo]
#define NX4  (S_LEN * EMB / 4)
#define NW4  (3 * EMB * EMB / 4)
#define NO4  (EMB * EMB / 4)
__global__ __launch_bounds__(256) void convert_all(
    const float* __restrict__ x, const float* __restrict__ wqkv,
    const float* __restrict__ wo, short* __restrict__ xb,
    short* __restrict__ wqkvb, short* __restrict__ wob)
{
    int i = blockIdx.x * 256 + threadIdx.x;
    const float* src; short* dst; int off;
    if (i < NX4)            { src = x;    dst = xb;    off = i; }
    else if (i < NX4 + NW4) { src = wqkv; dst = wqkvb; off = i - NX4; }
    else                    { src = wo;   dst = wob;   off = i - NX4 - NW4; }
    float4 v = ((const float4*)src)[off];
    short4v o = { f2bf(v.x), f2bf(v.y), f2bf(v.z), f2bf(v.w) };
    *(short4v*)(dst + (size_t)off * 4) = o;
}

// ---------------------------------------------------------------------------
// QKV GEMM: C = A·B^T + bias, 128(M)x96(N), BK=32, dbuf DMA, grid 24x32=768.
// Epilogue: ty==2 (V) -> direct V^T[h][d][row] 8B stores; ty 0/1 (Q/K) ->
// LDS round-trip (Ct[128][100] shorts, pad kills 8-way write conflicts) then
// short8 coalesced stores. Q pre-scaled by QSCALE.
// ---------------------------------------------------------------------------
__global__ __launch_bounds__(256) void gemm_qkv(
    const short* __restrict__ A, const short* __restrict__ B,
    const float* __restrict__ bias, short* __restrict__ Cv,
    int M, int N, int K)
{
    // unified LDS: As 2x4096, Bs 2x3072 shorts (28 KB); epilogue reuses it
    // as Ct[128][100] shorts (25.6 KB)
    __shared__ __align__(16) short smem[2 * 4096 + 2 * 3072];
    short* As0 = smem;
    short* Bs0 = smem + 2 * 4096;

    const int t = threadIdx.x;
    const int w = t >> 6, l = t & 63;
    const int quad = l >> 4, lane16 = l & 15;
    const int m0 = blockIdx.y * 128, n0 = blockIdx.x * 96;
    const int wm = (w >> 1) * 64, wn = (w & 1) * 48;

    f32x4 acc[4][3];
#pragma unroll
    for (int i = 0; i < 4; ++i)
#pragma unroll
        for (int j = 0; j < 3; ++j) acc[i][j] = (f32x4){0.f, 0.f, 0.f, 0.f};

    const int NKI = K >> 5;   // 24

    auto stage = [&](int ki, int b) {
        short* Asb = As0 + b * 4096;
        short* Bsb = Bs0 + b * 3072;
#pragma unroll
        for (int i = 0; i < 4; ++i) {
            int c = i * 256 + t;              // 0..1023; 896 used
            if (c < 512) {
                int r = c >> 2, kc = c & 3;
#if defined(__HIP_DEVICE_COMPILE__) && __has_builtin(__builtin_amdgcn_global_load_lds)
                __builtin_amdgcn_global_load_lds(
                    (const __attribute__((address_space(1))) void*)(A + (size_t)(m0 + r) * K + ki * 32 + kc * 8),
                    (__attribute__((address_space(3))) void*)(Asb + c * 8), 16, 0, 0);
#else
                *(short8*)(Asb + c * 8) = *(const short8*)(A + (size_t)(m0 + r) * K + ki * 32 + kc * 8);
#endif
            } else if (c < 896) {
                int cb = c - 512;
                int r = cb >> 2, kc = cb & 3;
#if defined(__HIP_DEVICE_COMPILE__) && __has_builtin(__builtin_amdgcn_global_load_lds)
                __builtin_amdgcn_global_load_lds(
                    (const __attribute__((address_space(1))) void*)(B + (size_t)(n0 + r) * K + ki * 32 + kc * 8),
                    (__attribute__((address_space(3))) void*)(Bsb + cb * 8), 16, 0, 0);
#else
                *(short8*)(Bsb + cb * 8) = *(const short8*)(B + (size_t)(n0 + r) * K + ki * 32 + kc * 8);
#endif
            }
        }
    };

    stage(0, 0);
    for (int kb = 0; kb < NKI; ++kb) {
        const int cur = kb & 1;
        __syncthreads();
        if (kb + 1 < NKI) stage(kb + 1, cur ^ 1);

        const short* Asb = As0 + cur * 4096;
        const short* Bsb = Bs0 + cur * 3072;
        short8 af[4], bfr[3];
#pragma unroll
        for (int mt = 0; mt < 4; ++mt)
            af[mt] = *(const short8*)(Asb + (wm + mt * 16 + lane16) * 32 + quad * 8);
#pragma unroll
        for (int nt = 0; nt < 3; ++nt)
            bfr[nt] = *(const short8*)(Bsb + (wn + nt * 16 + lane16) * 32 + quad * 8);
#pragma unroll
        for (int mt = 0; mt < 4; ++mt)
#pragma unroll
            for (int nt = 0; nt < 3; ++nt)
                acc[mt][nt] = __builtin_amdgcn_mfma_f32_16x16x32_bf16(
                    af[mt], bfr[nt], acc[mt][nt], 0, 0, 0);
    }

    __syncthreads();   // K-loop LDS reads done; smem free for epilogue tile
    short(*Ct)[100] = (short(*)[100])smem;   // pad 96->100: quads land 8 banks apart

#pragma unroll
    for (int nt = 0; nt < 3; ++nt) {
        int col = n0 + wn + nt * 16 + lane16;
        float bv = bias[col];
        int h = col / 192;
        int rem = col - h * 192;
        int ty = rem >> 6, d = rem & 63;
        if (ty == 2) {
            // V^T[h][d][row]: 4 consecutive rows per acc reg -> 8B store
            short* vt = Cv + ((size_t)2 * NH * S_LEN) * HD + ((size_t)h * HD + d) * S_LEN;
#pragma unroll
            for (int mt = 0; mt < 4; ++mt) {
                int row0 = m0 + wm + mt * 16 + quad * 4;
                short4v o = { f2bf(acc[mt][nt][0] + bv), f2bf(acc[mt][nt][1] + bv),
                              f2bf(acc[mt][nt][2] + bv), f2bf(acc[mt][nt][3] + bv) };
                *(short4v*)(vt + row0) = o;
            }
        } else {
            float s = (ty == 0) ? QSCALE : 1.f;
            int cl = wn + nt * 16 + lane16;   // col-local 0..95
#pragma unroll
            for (int mt = 0; mt < 4; ++mt) {
#pragma unroll
                for (int r = 0; r < 4; ++r)
                    Ct[wm + mt * 16 + quad * 4 + r][cl] = f2bf((acc[mt][nt][r] + bv) * s);
            }
        }
    }
    __syncthreads();

    // coalesced flush: 1536 short8-chunks (row 0..127, colgroup 0..11)
#pragma unroll
    for (int pass = 0; pass < 6; ++pass) {
        int c = pass * 256 + t;
        int row = c / 12, cg = c - row * 12;
        int col0 = n0 + cg * 8;               // 8-col group never straddles ty
        int h = col0 / 192;
        int rem = col0 - h * 192;
        int ty = rem >> 6;
        if (ty == 2) continue;                // V already stored directly
        int d0 = rem - ty * 64;
        short* dst = Cv + (((size_t)ty * NH + h) * S_LEN + (m0 + row)) * HD + d0;
        *(short8*)dst = *(const short8*)(&Ct[row][cg * 8]);
    }
}

// ---------------------------------------------------------------------------
// Windowed attention (unchanged). Q pre-scaled -> base-2 softmax. One 40960B
// LDS buffer: K (swizzled) for scores, then V^T for PV (DMA under softmax).
// ---------------------------------------------------------------------------
__global__ __launch_bounds__(256, 3) void attn_win(
    const short* __restrict__ qsplit, const int* __restrict__ wptr,
    short* __restrict__ attn_out)
{
    __shared__ __align__(16) short KS[320 * 64];   // 40960 B

    const int t = threadIdx.x;
    const int w = t >> 6, l = t & 63;
    const int quad = l >> 4, lane16 = l & 15;

    const int id = blockIdx.x;
    const int xcd = id & 7, j = id >> 3;
    const int h = j >> 3;
    const int q0 = ((xcd << 3) + (j & 7)) * QT;
    const int W = *wptr;
    const int kbase = q0 - WMAX;

    const short* Qh  = qsplit + (size_t)h * S_LEN * HD;
    const short* Kh  = qsplit + (size_t)(NH + h) * S_LEN * HD;
    const short* VtG = qsplit + (size_t)2 * NH * S_LEN * HD + (size_t)h * HD * S_LEN;

#pragma unroll
    for (int i = 0; i < 10; ++i) {
        int c = i * 256 + t;
        int r = c >> 3, gs = c & 7;
        int g = gs ^ (r & 7);
        int idx = min(max(kbase + r, 0), S_LEN - 1);
#if defined(__HIP_DEVICE_COMPILE__) && __has_builtin(__builtin_amdgcn_global_load_lds)
        __builtin_amdgcn_global_load_lds(
            (const __attribute__((address_space(1))) void*)(Kh + (size_t)idx * HD + g * 8),
            (__attribute__((address_space(3))) void*)(KS + c * 8), 16, 0, 0);
#else
        *(short8*)(KS + c * 8) = *(const short8*)(Kh + (size_t)idx * HD + g * 8);
#endif
    }
    const int qi = q0 + w * 16 + lane16;
    const short* qp = Qh + (size_t)qi * HD;
    short8 bq0 = *(const short8*)(qp + quad * 8);
    short8 bq1 = *(const short8*)(qp + 32 + quad * 8);

    __syncthreads();   // K resident

    f32x4 sc[NKT];
    const int d7 = lane16 & 7;
    const int s0 = (quad ^ d7) * 8;
    const int s1 = ((quad + 4) ^ d7) * 8;
#pragma unroll
    for (int kt = 0; kt < NKT; ++kt) {
        const short* kp = KS + (kt * 16 + lane16) * 64;
        short8 a0 = *(const short8*)(kp + s0);
        short8 a1 = *(const short8*)(kp + s1);
        f32x4 a = (f32x4){0.f, 0.f, 0.f, 0.f};
        a = __builtin_amdgcn_mfma_f32_16x16x32_bf16(a0, bq0, a, 0, 0, 0);
        a = __builtin_amdgcn_mfma_f32_16x16x32_bf16(a1, bq1, a, 0, 0, 0);
        sc[kt] = a;
    }

    __syncthreads();   // WAR: K reads done; KS free for V^T

#pragma unroll
    for (int i = 0; i < 10; ++i) {
        int c = i * 256 + t;
        int d = c / 40;
        int slot = c - d * 40;
        int sg = slot >> 3, s = slot & 7;
        int g = s ^ (d & 7);
        int key0 = kbase + sg * 64 + g * 8;
        key0 = min(max(key0, 0), S_LEN - 8);
#if defined(__HIP_DEVICE_COMPILE__) && __has_builtin(__builtin_amdgcn_global_load_lds)
        __builtin_amdgcn_global_load_lds(
            (const __attribute__((address_space(1))) void*)(VtG + (size_t)d * S_LEN + key0),
            (__attribute__((address_space(3))) void*)(KS + c * 8), 16, 0, 0);
#else
        *(short8*)(KS + c * 8) = *(const short8*)(VtG + (size_t)d * S_LEN + key0);
#endif
    }

    float m = -1e30f;
#pragma unroll
    for (int kt = 0; kt < NKT; ++kt) {
#pragma unroll
        for (int r = 0; r < 4; ++r) {
            int key = kbase + kt * 16 + quad * 4 + r;
            int dd = qi - key;
            int ad = dd < 0 ? -dd : dd;
            bool valid = ((unsigned)key < S_LEN) && (ad <= W);
            float s = valid ? sc[kt][r] : -1e30f;
            sc[kt][r] = s;
            m = fmaxf(m, s);
        }
    }
    m = fmaxf(m, __shfl_xor(m, 16, 64));
    m = fmaxf(m, __shfl_xor(m, 32, 64));

    float lsum = 0.f;
#pragma unroll
    for (int kt = 0; kt < NKT; ++kt) {
#pragma unroll
        for (int r = 0; r < 4; ++r) {
            float p = exp2f(sc[kt][r] - m);
            sc[kt][r] = p;
            lsum += p;
        }
    }
    lsum += __shfl_xor(lsum, 16, 64);
    lsum += __shfl_xor(lsum, 32, 64);
    const float rl = 1.f / fmaxf(lsum, 1e-30f);

    __syncthreads();   // V^T resident

    f32x4 oacc[4];
#pragma unroll
    for (int nt = 0; nt < 4; ++nt) oacc[nt] = (f32x4){0.f, 0.f, 0.f, 0.f};

#pragma unroll
    for (int kt = 0; kt < NKT; ++kt) {
        short4v pb = { f2bf(sc[kt][0]), f2bf(sc[kt][1]),
                       f2bf(sc[kt][2]), f2bf(sc[kt][3]) };
        int G = kt * 2 + (quad >> 1);
        int off = (G >> 3) * 64 + ((G & 7) ^ d7) * 8 + (quad & 1) * 4;
#pragma unroll
        for (int nt = 0; nt < 4; ++nt) {
            short4v va = *(const short4v*)(KS + (nt * 16 + lane16) * 320 + off);
            oacc[nt] = MFMA16(va, pb, oacc[nt]);
        }
    }

#pragma unroll
    for (int nt = 0; nt < 4; ++nt) {
        short4v ob = { f2bf(oacc[nt][0] * rl), f2bf(oacc[nt][1] * rl),
                       f2bf(oacc[nt][2] * rl), f2bf(oacc[nt][3] * rl) };
        *(short4v*)(attn_out + (size_t)qi * EMB + h * HD + nt * 16 + quad * 4) = ob;
    }
}

// ---------------------------------------------------------------------------
// Output projection GEMM: 64x64 tile, BK=64, dbuf DMA w/ source-XOR swizzle.
// Epilogue via LDS round-trip (Ct[64][66] fp32) -> float4 coalesced stores.
// ---------------------------------------------------------------------------
__global__ __launch_bounds__(256) void gemm_out64(
    const short* __restrict__ A, const short* __restrict__ B,
    const float* __restrict__ bias, float* __restrict__ C,
    int M, int N, int K)
{
    __shared__ __align__(16) short As[2][4352];   // 17408 B (epilogue Ct needs 16896)
    __shared__ __align__(16) short Bs[2][4096];

    const int t = threadIdx.x;
    const int w = t >> 6, l = t & 63;
    const int quad = l >> 4, lane16 = l & 15;
    const int m0 = blockIdx.y * 64, n0 = blockIdx.x * 64;
    const int wm = (w >> 1) * 32, wn = (w & 1) * 32;

    f32x4 acc[2][2];
#pragma unroll
    for (int i = 0; i < 2; ++i)
#pragma unroll
        for (int j = 0; j < 2; ++j) acc[i][j] = (f32x4){0.f, 0.f, 0.f, 0.f};

    const int NKI = K >> 6;   // 12

    auto stage = [&](int ki, int b) {
#pragma unroll
        for (int i = 0; i < 2; ++i) {
            int c = i * 256 + t;
            int r = c >> 3, kc = c & 7;
            int g = kc ^ (r & 7);
#if defined(__HIP_DEVICE_COMPILE__) && __has_builtin(__builtin_amdgcn_global_load_lds)
            __builtin_amdgcn_global_load_lds(
                (const __attribute__((address_space(1))) void*)(A + (size_t)(m0 + r) * K + ki * 64 + g * 8),
                (__attribute__((address_space(3))) void*)(As[b] + c * 8), 16, 0, 0);
            __builtin_amdgcn_global_load_lds(
                (const __attribute__((address_space(1))) void*)(B + (size_t)(n0 + r) * K + ki * 64 + g * 8),
                (__attribute__((address_space(3))) void*)(Bs[b] + c * 8), 16, 0, 0);
#else
            *(short8*)(As[b] + c * 8) = *(const short8*)(A + (size_t)(m0 + r) * K + ki * 64 + g * 8);
            *(short8*)(Bs[b] + c * 8) = *(const short8*)(B + (size_t)(n0 + r) * K + ki * 64 + g * 8);
#endif
        }
    };

    stage(0, 0);
    for (int kb = 0; kb < NKI; ++kb) {
        const int cur = kb & 1;
        __syncthreads();
        if (kb + 1 < NKI) stage(kb + 1, cur ^ 1);

#pragma unroll
        for (int ks = 0; ks < 2; ++ks) {
            short8 af[2], bfr[2];
#pragma unroll
            for (int mt = 0; mt < 2; ++mt) {
                int row = wm + mt * 16 + lane16;
                int slot = (ks * 4 + quad) ^ (row & 7);
                af[mt] = *(const short8*)(As[cur] + row * 64 + slot * 8);
            }
#pragma unroll
            for (int nt = 0; nt < 2; ++nt) {
                int row = wn + nt * 16 + lane16;
                int slot = (ks * 4 + quad) ^ (row & 7);
                bfr[nt] = *(const short8*)(Bs[cur] + row * 64 + slot * 8);
            }
#pragma unroll
            for (int mt = 0; mt < 2; ++mt)
#pragma unroll
                for (int nt = 0; nt < 2; ++nt)
                    acc[mt][nt] = __builtin_amdgcn_mfma_f32_16x16x32_bf16(
                        af[mt], bfr[nt], acc[mt][nt], 0, 0, 0);
        }
    }

    __syncthreads();   // K-loop LDS reads done
    float(*Ct)[66] = (float(*)[66])As;   // 64x66 fp32, pad kills conflicts

#pragma unroll
    for (int nt = 0; nt < 2; ++nt) {
        int cl = wn + nt * 16 + lane16;
        float bv = bias[n0 + cl];
#pragma unroll
        for (int mt = 0; mt < 2; ++mt) {
#pragma unroll
            for (int r = 0; r < 4; ++r)
                Ct[wm + mt * 16 + quad * 4 + r][cl] = acc[mt][nt][r] + bv;
        }
    }
    __syncthreads();

    // coalesced flush: 1024 float4-chunks (row 0..63, colgroup 0..15)
#pragma unroll
    for (int pass = 0; pass < 4; ++pass) {
        int c = pass * 256 + t;
        int row = c >> 4, cg = c & 15;
        float4 v = { Ct[row][cg * 4], Ct[row][cg * 4 + 1],
                     Ct[row][cg * 4 + 2], Ct[row][cg * 4 + 3] };
        *(float4*)(C + (size_t)(m0 + row) * N + n0 + cg * 4) = v;
    }
}

extern "C" void kernel_launch(void* const* d_in, const int* in_sizes, int n_in,
                              void* d_out, int out_size, void* d_ws, size_t ws_size,
                              hipStream_t stream) {
    const float* x    = (const float*)d_in[0];
    const float* Wqkv = (const float*)d_in[1];
    const float* bqkv = (const float*)d_in[2];
    const float* Wo   = (const float*)d_in[3];
    const float* bo   = (const float*)d_in[4];
    const int*   wptr = (const int*)d_in[5];

    float* out = (float*)d_out;

    short* xb     = (short*)d_ws;
    short* wqkvb  = xb     + (size_t)S_LEN * EMB;
    short* wob    = wqkvb  + (size_t)3 * EMB * EMB;
    short* qsplit = wob    + (size_t)EMB * EMB;          // Q|K row-major, V^T
    short* attn   = qsplit + (size_t)3 * NH * S_LEN * HD;

    dim3 blk(256);
    convert_all<<<dim3((NX4 + NW4 + NO4) / 256), blk, 0, stream>>>(
        x, Wqkv, Wo, xb, wqkvb, wob);
    gemm_qkv<<<dim3(2304 / 96, S_LEN / 128), blk, 0, stream>>>(
        xb, wqkvb, bqkv, qsplit, S_LEN, 2304, EMB);
    attn_win<<<dim3(S_LEN / QT * NH), blk, 0, stream>>>(qsplit, wptr, attn);
    gemm_out64<<<dim3(EMB / 64, S_LEN / 64), blk, 0, stream>>>(
        attn, wob, bo, out, S_LEN, EMB, EMB);
}